// Round 2
// baseline (1231.115 us; speedup 1.0000x reference)
//
#include <hip/hip_runtime.h>

// ---------------------------------------------------------------------------
// OctreeResBlock on MI355X (gfx950), round 1: fuse BN column-stats into GEMM
// epilogues (round-0 profile: 4x colstats = 540us of 871us).
//   h  = x^T                              [N,256]  (bf16)
//   c1 = relu(bn(h @ W1a^T))              [N,128]
//   c2 = relu(bn(octree_conv(c1)))        [N,128]
//   c3 = bn(c2 @ W1b^T)                   [N,512]
//   sc = bn(h @ Wc^T)                     [N,512]
//   out = relu(c3 + sc)^T                 [512,N] fp32
// ---------------------------------------------------------------------------

typedef __bf16 bf16x8 __attribute__((ext_vector_type(8)));
typedef float f32x4 __attribute__((ext_vector_type(4)));
typedef unsigned short u16x8 __attribute__((ext_vector_type(8)));

__device__ __forceinline__ unsigned short f2bfu(float f) {
  union { float f; unsigned u; } v; v.f = f;
  unsigned r = v.u + 0x7fffu + ((v.u >> 16) & 1u);   // round-to-nearest-even
  return (unsigned short)(r >> 16);
}
__device__ __forceinline__ float bfu2f(unsigned short s) {
  union { unsigned u; float f; } v; v.u = ((unsigned)s) << 16;
  return v.f;
}

// --- weights prep: fp32 -> bf16; W3 [k][c][d] -> w3t [k][d][c] --------------
__global__ __launch_bounds__(256) void prep_weights(
    const float* __restrict__ W1a, const float* __restrict__ W3,
    const float* __restrict__ W1b, const float* __restrict__ Wc,
    unsigned short* __restrict__ w1a, unsigned short* __restrict__ w3t,
    unsigned short* __restrict__ w1b, unsigned short* __restrict__ wc) {
  int i = blockIdx.x * 256 + threadIdx.x;
  int stride = gridDim.x * 256;
  for (; i < 442368; i += stride) {
    if (i < 32768)  w1a[i] = f2bfu(W1a[i]);
    if (i < 65536)  w1b[i] = f2bfu(W1b[i]);
    if (i < 131072) wc[i]  = f2bfu(Wc[i]);
    int k = i >> 14, rr = i & 16383;
    int d = rr >> 7, c = rr & 127;
    w3t[i] = f2bfu(W3[(k << 14) + (c << 7) + d]);
  }
}

// --- x [256][M] fp32 -> h [M][256] bf16 (LDS tile transpose) ----------------
__global__ __launch_bounds__(256) void transpose_x(
    const float* __restrict__ x, unsigned short* __restrict__ h, int M) {
  __shared__ float tile[64][65];
  int n0 = blockIdx.x * 64, c0 = blockIdx.y * 64;
  int t = threadIdx.x;
  int nl = t & 63;
#pragma unroll
  for (int i = 0; i < 16; ++i) {
    int cl = i * 4 + (t >> 6);
    int n = n0 + nl;
    tile[cl][nl] = (n < M) ? x[(size_t)(c0 + cl) * M + n] : 0.f;
  }
  __syncthreads();
  int cl = t & 63;
#pragma unroll
  for (int i = 0; i < 16; ++i) {
    int nl2 = i * 4 + (t >> 6);
    int n = n0 + nl2;
    if (n < M) h[(size_t)n * 256 + c0 + cl] = f2bfu(tile[cl][nl2]);
  }
}

// --- generic GEMM: C[M][Nc] = A[M][Kd] * W[Nc][Kd]^T, all bf16 --------------
// 64x64 tile, 4 waves; epilogue writes per-rowblock column sum/sumsq partials.
__global__ __launch_bounds__(256) void gemm_bt(
    const unsigned short* __restrict__ A, const unsigned short* __restrict__ W,
    unsigned short* __restrict__ C, float* __restrict__ partials,
    int M, int Kd, int Nc) {
  __shared__ unsigned short sA[64 * 40];  // stride 40 elems (80B): ~2-way conflicts only
  __shared__ unsigned short sB[64 * 40];
  __shared__ float sStat[4][2][64];
  int t = threadIdx.x, wave = t >> 6, lane = t & 63;
  int m0 = blockIdx.x * 64, n0 = blockIdx.y * 64;
  f32x4 acc[4] = {};
  int r = t >> 2, ch = (t & 3) * 8;
  int arow = m0 + r;
  bool aval = arow < M;
  const unsigned short* Ar = A + (size_t)arow * Kd + ch;
  const unsigned short* Wr = W + (size_t)(n0 + r) * Kd + ch;
  int aoff = (wave * 16 + (lane & 15)) * 40 + (lane >> 4) * 8;
  int boffb = (lane & 15) * 40 + (lane >> 4) * 8;
  for (int k0 = 0; k0 < Kd; k0 += 32) {
    u16x8 av = {0, 0, 0, 0, 0, 0, 0, 0};
    if (aval) av = *(const u16x8*)(Ar + k0);
    u16x8 bv = *(const u16x8*)(Wr + k0);
    *(u16x8*)(sA + r * 40 + ch) = av;
    *(u16x8*)(sB + r * 40 + ch) = bv;
    __syncthreads();
    bf16x8 a = __builtin_bit_cast(bf16x8, *(const u16x8*)(sA + aoff));
#pragma unroll
    for (int nb = 0; nb < 4; ++nb) {
      bf16x8 b = __builtin_bit_cast(bf16x8, *(const u16x8*)(sB + boffb + nb * 16 * 40));
      acc[nb] = __builtin_amdgcn_mfma_f32_16x16x32_bf16(a, b, acc[nb], 0, 0, 0);
    }
    __syncthreads();
  }
  int rb = wave * 16 + (lane >> 4) * 4;
  int col = lane & 15;
#pragma unroll
  for (int nb = 0; nb < 4; ++nb) {
    float s = 0.f, q = 0.f;
#pragma unroll
    for (int i = 0; i < 4; ++i) {
      int n = m0 + rb + i;
      unsigned short u = f2bfu(acc[nb][i]);
      if (n < M) C[(size_t)n * Nc + n0 + nb * 16 + col] = u;
      float v = bfu2f(u);   // rows >= M have zero A -> zero acc -> contribute 0
      s += v; q += v * v;
    }
    s += __shfl_xor(s, 16); s += __shfl_xor(s, 32);
    q += __shfl_xor(q, 16); q += __shfl_xor(q, 32);
    if (lane < 16) {
      sStat[wave][0][nb * 16 + lane] = s;
      sStat[wave][1][nb * 16 + lane] = q;
    }
  }
  __syncthreads();
  if (t < 64) {
    float s = sStat[0][0][t] + sStat[1][0][t] + sStat[2][0][t] + sStat[3][0][t];
    float q = sStat[0][1][t] + sStat[1][1][t] + sStat[2][1][t] + sStat[3][1][t];
    partials[(size_t)blockIdx.x * (2 * Nc) + n0 + t] = s;
    partials[(size_t)blockIdx.x * (2 * Nc) + Nc + n0 + t] = q;
  }
}

// --- octree conv: c2p[n][d] = sum_k sum_c c1[neigh[n][k]][c] * w3t[k][d][c] -
__global__ __launch_bounds__(256) void octree_gemm(
    const unsigned short* __restrict__ c1, const int* __restrict__ neigh,
    const unsigned short* __restrict__ w3t, unsigned short* __restrict__ c2p,
    float* __restrict__ partials, int M) {
  __shared__ unsigned short sA[64 * 40];
  __shared__ unsigned short sB[128 * 40];
  __shared__ int nidx[64 * 27];
  __shared__ float sStat[4][2][128];
  int t = threadIdx.x, wave = t >> 6, lane = t & 63;
  int m0 = blockIdx.x * 64;
  for (int i = t; i < 64 * 27; i += 256) {
    int row = i / 27;
    nidx[i] = (m0 + row < M) ? neigh[(size_t)m0 * 27 + i] : M;  // M == empty
  }
  __syncthreads();
  f32x4 acc[8] = {};
  int r = t >> 2, ch = (t & 3) * 8;
  int aoff = (wave * 16 + (lane & 15)) * 40 + (lane >> 4) * 8;
  int boffb = (lane & 15) * 40 + (lane >> 4) * 8;
  int jb = t >> 2, chb = (t & 3) * 8;
  for (int k = 0; k < 27; ++k) {
    int mrow = nidx[r * 27 + k];
    const unsigned short* arp = c1 + (size_t)mrow * 128 + ch;
    const unsigned short* wk = w3t + (size_t)k * 16384;
#pragma unroll
    for (int ccq = 0; ccq < 4; ++ccq) {
      int cc = ccq * 32;
      u16x8 av = {0, 0, 0, 0, 0, 0, 0, 0};
      if (mrow < M) av = *(const u16x8*)(arp + cc);
      *(u16x8*)(sA + r * 40 + ch) = av;
      *(u16x8*)(sB + jb * 40 + chb) = *(const u16x8*)(wk + (size_t)jb * 128 + cc + chb);
      *(u16x8*)(sB + (jb + 64) * 40 + chb) = *(const u16x8*)(wk + (size_t)(jb + 64) * 128 + cc + chb);
      __syncthreads();
      bf16x8 a = __builtin_bit_cast(bf16x8, *(const u16x8*)(sA + aoff));
#pragma unroll
      for (int nb = 0; nb < 8; ++nb) {
        bf16x8 b = __builtin_bit_cast(bf16x8, *(const u16x8*)(sB + boffb + nb * 16 * 40));
        acc[nb] = __builtin_amdgcn_mfma_f32_16x16x32_bf16(a, b, acc[nb], 0, 0, 0);
      }
      __syncthreads();
    }
  }
  int rb = wave * 16 + (lane >> 4) * 4;
  int col = lane & 15;
#pragma unroll
  for (int nb = 0; nb < 8; ++nb) {
    float s = 0.f, q = 0.f;
#pragma unroll
    for (int i = 0; i < 4; ++i) {
      int n = m0 + rb + i;
      unsigned short u = f2bfu(acc[nb][i]);
      if (n < M) c2p[(size_t)n * 128 + nb * 16 + col] = u;
      float v = bfu2f(u);
      s += v; q += v * v;
    }
    s += __shfl_xor(s, 16); s += __shfl_xor(s, 32);
    q += __shfl_xor(q, 16); q += __shfl_xor(q, 32);
    if (lane < 16) {
      sStat[wave][0][nb * 16 + lane] = s;
      sStat[wave][1][nb * 16 + lane] = q;
    }
  }
  __syncthreads();
  if (t < 128) {
    float s = sStat[0][0][t] + sStat[1][0][t] + sStat[2][0][t] + sStat[3][0][t];
    float q = sStat[0][1][t] + sStat[1][1][t] + sStat[2][1][t] + sStat[3][1][t];
    partials[(size_t)blockIdx.x * 256 + t] = s;
    partials[(size_t)blockIdx.x * 256 + 128 + t] = q;
  }
}

// --- reduce partials -> scale/shift: ss[c]=g*rsqrt(var+eps), ss[C+c]=b-mu*sc
__global__ void bn_finalize(const float* __restrict__ partials, int nb, int C, int M,
                            const float* __restrict__ g, const float* __restrict__ bt,
                            float* __restrict__ ss) {
  int c = blockIdx.x * blockDim.x + threadIdx.x;
  if (c >= C) return;
  float s = 0.f, s2 = 0.f;
  for (int b = 0; b < nb; ++b) {
    s += partials[(size_t)b * 2 * C + c];
    s2 += partials[(size_t)b * 2 * C + C + c];
  }
  float mean = s / (float)M;
  float var = s2 / (float)M - mean * mean;
  float sc = g[c] * rsqrtf(var + 1e-5f);
  ss[c] = sc;
  ss[C + c] = bt[c] - mean * sc;
}

// --- elementwise BN + ReLU, bf16 in/out -------------------------------------
__global__ __launch_bounds__(256) void bnrelu(
    const unsigned short* __restrict__ P, const float* __restrict__ ss,
    unsigned short* __restrict__ Aout, int total, int Cmask) {
  int i = (blockIdx.x * 256 + threadIdx.x) * 8;
  if (i >= total) return;
  u16x8 v = *(const u16x8*)(P + i);
  int c0 = i & Cmask;
  int C = Cmask + 1;
  u16x8 o;
#pragma unroll
  for (int j = 0; j < 8; ++j) {
    float f = bfu2f(v[j]) * ss[c0 + j] + ss[C + c0 + j];
    o[j] = f2bfu(fmaxf(f, 0.f));
  }
  *(u16x8*)(Aout + i) = o;
}

// --- final: out[c][n] = relu(bn3(c3p) + bnsc(scp)), transposed fp32 write ---
__global__ __launch_bounds__(256) void final_out(
    const unsigned short* __restrict__ c3p, const unsigned short* __restrict__ scp,
    const float* __restrict__ ss3, const float* __restrict__ sssc,
    float* __restrict__ out, int M) {
  __shared__ float tile[64][65];
  int n0 = blockIdx.x * 64, c0 = blockIdx.y * 64;
  int t = threadIdx.x;
  int cl = t & 63;
#pragma unroll
  for (int i = 0; i < 16; ++i) {
    int nl = i * 4 + (t >> 6);
    int n = n0 + nl;
    float v = 0.f;
    if (n < M) {
      int c = c0 + cl;
      float a = bfu2f(c3p[(size_t)n * 512 + c]) * ss3[c] + ss3[512 + c];
      float b = bfu2f(scp[(size_t)n * 512 + c]) * sssc[c] + sssc[512 + c];
      v = fmaxf(a + b, 0.f);
    }
    tile[nl][cl] = v;
  }
  __syncthreads();
  int nl = t & 63;
#pragma unroll
  for (int i = 0; i < 16; ++i) {
    int cl2 = i * 4 + (t >> 6);
    int n = n0 + nl;
    if (n < M) out[(size_t)(c0 + cl2) * M + n0 + nl] = tile[nl][cl2];
  }
}

extern "C" void kernel_launch(void* const* d_in, const int* in_sizes, int n_in,
                              void* d_out, int out_size, void* d_ws, size_t ws_size,
                              hipStream_t stream) {
  const float* x   = (const float*)d_in[0];
  const int* neigh = (const int*)d_in[1];
  const float* W1a = (const float*)d_in[2];
  const float* g1a = (const float*)d_in[3];
  const float* b1a = (const float*)d_in[4];
  const float* W3  = (const float*)d_in[5];
  const float* g3  = (const float*)d_in[6];
  const float* b3  = (const float*)d_in[7];
  const float* W1b = (const float*)d_in[8];
  const float* g1b = (const float*)d_in[9];
  const float* b1b = (const float*)d_in[10];
  const float* Wc  = (const float*)d_in[11];
  const float* gc  = (const float*)d_in[12];
  const float* bc  = (const float*)d_in[13];
  float* out = (float*)d_out;

  const int M = in_sizes[1] / 27;          // 60000 nodes
  const int MT = (M + 63) / 64;            // 938 row tiles

  char* ws = (char*)d_ws;
  unsigned short* h   = (unsigned short*)(ws + 0);           // [M][256] bf16
  unsigned short* wA  = (unsigned short*)(ws + 30720000);    // activations c1/c2 [M][128]
  unsigned short* wP  = (unsigned short*)(ws + 46080000);    // pre-activations [M][128]
  unsigned short* c3p = (unsigned short*)(ws + 61440000);    // [M][512]
  unsigned short* scp = (unsigned short*)(ws + 122880000);   // [M][512]
  unsigned short* w1a = (unsigned short*)(ws + 184320000);   // [128][256]
  unsigned short* w3t = (unsigned short*)(ws + 184385536);   // [27][128][128] d-major
  unsigned short* w1b = (unsigned short*)(ws + 185270272);   // [512][128]
  unsigned short* wc  = (unsigned short*)(ws + 185401344);   // [512][256]
  float* ss1  = (float*)(ws + 185663488);
  float* ss2  = (float*)(ws + 185667584);
  float* ss3  = (float*)(ws + 185671680);
  float* sssc = (float*)(ws + 185679872);

  // Partials live in ws regions that are dead at their point of use:
  float* part12 = (float*)c3p;   // stage-1/2 stats (c3p not yet written)
  float* part3  = (float*)scp;   // stage-3 stats (read by fin3 before gemmsc writes scp)
  float* partsc = (float*)wP;    // shortcut stats (wP dead after bnrelu2)

  prep_weights<<<1728, 256, 0, stream>>>(W1a, W3, W1b, Wc, w1a, w3t, w1b, wc);
  transpose_x<<<dim3(MT, 4), 256, 0, stream>>>(x, h, M);

  const int bnGrid = (M * 128 / 8 + 255) / 256;

  // c1 = relu(bn(h @ W1a^T))
  gemm_bt<<<dim3(MT, 2), 256, 0, stream>>>(h, w1a, wP, part12, M, 256, 128);
  bn_finalize<<<1, 256, 0, stream>>>(part12, MT, 128, M, g1a, b1a, ss1);
  bnrelu<<<bnGrid, 256, 0, stream>>>(wP, ss1, wA, M * 128, 127);

  // c2 = relu(bn(octree_conv(c1)))
  octree_gemm<<<MT, 256, 0, stream>>>(wA, neigh, w3t, wP, part12, M);
  bn_finalize<<<1, 256, 0, stream>>>(part12, MT, 128, M, g3, b3, ss2);
  bnrelu<<<bnGrid, 256, 0, stream>>>(wP, ss2, wA, M * 128, 127);

  // c3_pre = c2 @ W1b^T (stats -> part3, consumed before scp is written)
  gemm_bt<<<dim3(MT, 8), 256, 0, stream>>>(wA, w1b, c3p, part3, M, 128, 512);
  bn_finalize<<<2, 256, 0, stream>>>(part3, MT, 512, M, g1b, b1b, ss3);

  // sc_pre = h @ Wc^T
  gemm_bt<<<dim3(MT, 8), 256, 0, stream>>>(h, wc, scp, partsc, M, 256, 512);
  bn_finalize<<<2, 256, 0, stream>>>(partsc, MT, 512, M, gc, bc, sssc);

  // out = relu(bn(c3_pre) + bn(sc_pre)), transposed to [512][M]
  final_out<<<dim3(MT, 8), 256, 0, stream>>>(c3p, scp, ss3, sssc, out, M);
}

// Round 3
// 351.186 us; speedup vs baseline: 3.5056x; 3.5056x over previous
//
#include <hip/hip_runtime.h>

// ---------------------------------------------------------------------------
// OctreeResBlock on MI355X (gfx950), round 2: parallel bn_finalize
// (round-1 profile: 4x bn_finalize @ ~240us = 960us — serial nb=938 loop on
// 1-2 blocks). Now: one block per channel, 256-thread tree reduction.
// ---------------------------------------------------------------------------

typedef __bf16 bf16x8 __attribute__((ext_vector_type(8)));
typedef float f32x4 __attribute__((ext_vector_type(4)));
typedef unsigned short u16x8 __attribute__((ext_vector_type(8)));

__device__ __forceinline__ unsigned short f2bfu(float f) {
  union { float f; unsigned u; } v; v.f = f;
  unsigned r = v.u + 0x7fffu + ((v.u >> 16) & 1u);   // round-to-nearest-even
  return (unsigned short)(r >> 16);
}
__device__ __forceinline__ float bfu2f(unsigned short s) {
  union { unsigned u; float f; } v; v.u = ((unsigned)s) << 16;
  return v.f;
}

// --- weights prep: fp32 -> bf16; W3 [k][c][d] -> w3t [k][d][c] --------------
__global__ __launch_bounds__(256) void prep_weights(
    const float* __restrict__ W1a, const float* __restrict__ W3,
    const float* __restrict__ W1b, const float* __restrict__ Wc,
    unsigned short* __restrict__ w1a, unsigned short* __restrict__ w3t,
    unsigned short* __restrict__ w1b, unsigned short* __restrict__ wc) {
  int i = blockIdx.x * 256 + threadIdx.x;
  int stride = gridDim.x * 256;
  for (; i < 442368; i += stride) {
    if (i < 32768)  w1a[i] = f2bfu(W1a[i]);
    if (i < 65536)  w1b[i] = f2bfu(W1b[i]);
    if (i < 131072) wc[i]  = f2bfu(Wc[i]);
    int k = i >> 14, rr = i & 16383;
    int d = rr >> 7, c = rr & 127;
    w3t[i] = f2bfu(W3[(k << 14) + (c << 7) + d]);
  }
}

// --- x [256][M] fp32 -> h [M][256] bf16 (LDS tile transpose) ----------------
__global__ __launch_bounds__(256) void transpose_x(
    const float* __restrict__ x, unsigned short* __restrict__ h, int M) {
  __shared__ float tile[64][65];
  int n0 = blockIdx.x * 64, c0 = blockIdx.y * 64;
  int t = threadIdx.x;
  int nl = t & 63;
#pragma unroll
  for (int i = 0; i < 16; ++i) {
    int cl = i * 4 + (t >> 6);
    int n = n0 + nl;
    tile[cl][nl] = (n < M) ? x[(size_t)(c0 + cl) * M + n] : 0.f;
  }
  __syncthreads();
  int cl = t & 63;
#pragma unroll
  for (int i = 0; i < 16; ++i) {
    int nl2 = i * 4 + (t >> 6);
    int n = n0 + nl2;
    if (n < M) h[(size_t)n * 256 + c0 + cl] = f2bfu(tile[cl][nl2]);
  }
}

// --- generic GEMM: C[M][Nc] = A[M][Kd] * W[Nc][Kd]^T, all bf16 --------------
// 64x64 tile, 4 waves; epilogue writes per-rowblock column sum/sumsq partials.
__global__ __launch_bounds__(256) void gemm_bt(
    const unsigned short* __restrict__ A, const unsigned short* __restrict__ W,
    unsigned short* __restrict__ C, float* __restrict__ partials,
    int M, int Kd, int Nc) {
  __shared__ unsigned short sA[64 * 40];  // stride 40 elems (80B): ~2-way conflicts only
  __shared__ unsigned short sB[64 * 40];
  __shared__ float sStat[4][2][64];
  int t = threadIdx.x, wave = t >> 6, lane = t & 63;
  int m0 = blockIdx.x * 64, n0 = blockIdx.y * 64;
  f32x4 acc[4] = {};
  int r = t >> 2, ch = (t & 3) * 8;
  int arow = m0 + r;
  bool aval = arow < M;
  const unsigned short* Ar = A + (size_t)arow * Kd + ch;
  const unsigned short* Wr = W + (size_t)(n0 + r) * Kd + ch;
  int aoff = (wave * 16 + (lane & 15)) * 40 + (lane >> 4) * 8;
  int boffb = (lane & 15) * 40 + (lane >> 4) * 8;
  for (int k0 = 0; k0 < Kd; k0 += 32) {
    u16x8 av = {0, 0, 0, 0, 0, 0, 0, 0};
    if (aval) av = *(const u16x8*)(Ar + k0);
    u16x8 bv = *(const u16x8*)(Wr + k0);
    *(u16x8*)(sA + r * 40 + ch) = av;
    *(u16x8*)(sB + r * 40 + ch) = bv;
    __syncthreads();
    bf16x8 a = __builtin_bit_cast(bf16x8, *(const u16x8*)(sA + aoff));
#pragma unroll
    for (int nb = 0; nb < 4; ++nb) {
      bf16x8 b = __builtin_bit_cast(bf16x8, *(const u16x8*)(sB + boffb + nb * 16 * 40));
      acc[nb] = __builtin_amdgcn_mfma_f32_16x16x32_bf16(a, b, acc[nb], 0, 0, 0);
    }
    __syncthreads();
  }
  int rb = wave * 16 + (lane >> 4) * 4;
  int col = lane & 15;
#pragma unroll
  for (int nb = 0; nb < 4; ++nb) {
    float s = 0.f, q = 0.f;
#pragma unroll
    for (int i = 0; i < 4; ++i) {
      int n = m0 + rb + i;
      unsigned short u = f2bfu(acc[nb][i]);
      if (n < M) C[(size_t)n * Nc + n0 + nb * 16 + col] = u;
      float v = bfu2f(u);   // rows >= M have zero A -> zero acc -> contribute 0
      s += v; q += v * v;
    }
    s += __shfl_xor(s, 16); s += __shfl_xor(s, 32);
    q += __shfl_xor(q, 16); q += __shfl_xor(q, 32);
    if (lane < 16) {
      sStat[wave][0][nb * 16 + lane] = s;
      sStat[wave][1][nb * 16 + lane] = q;
    }
  }
  __syncthreads();
  if (t < 64) {
    float s = sStat[0][0][t] + sStat[1][0][t] + sStat[2][0][t] + sStat[3][0][t];
    float q = sStat[0][1][t] + sStat[1][1][t] + sStat[2][1][t] + sStat[3][1][t];
    partials[(size_t)blockIdx.x * (2 * Nc) + n0 + t] = s;
    partials[(size_t)blockIdx.x * (2 * Nc) + Nc + n0 + t] = q;
  }
}

// --- octree conv: c2p[n][d] = sum_k sum_c c1[neigh[n][k]][c] * w3t[k][d][c] -
__global__ __launch_bounds__(256) void octree_gemm(
    const unsigned short* __restrict__ c1, const int* __restrict__ neigh,
    const unsigned short* __restrict__ w3t, unsigned short* __restrict__ c2p,
    float* __restrict__ partials, int M) {
  __shared__ unsigned short sA[64 * 40];
  __shared__ unsigned short sB[128 * 40];
  __shared__ int nidx[64 * 27];
  __shared__ float sStat[4][2][128];
  int t = threadIdx.x, wave = t >> 6, lane = t & 63;
  int m0 = blockIdx.x * 64;
  for (int i = t; i < 64 * 27; i += 256) {
    int row = i / 27;
    nidx[i] = (m0 + row < M) ? neigh[(size_t)m0 * 27 + i] : M;  // M == empty
  }
  __syncthreads();
  f32x4 acc[8] = {};
  int r = t >> 2, ch = (t & 3) * 8;
  int aoff = (wave * 16 + (lane & 15)) * 40 + (lane >> 4) * 8;
  int boffb = (lane & 15) * 40 + (lane >> 4) * 8;
  int jb = t >> 2, chb = (t & 3) * 8;
  for (int k = 0; k < 27; ++k) {
    int mrow = nidx[r * 27 + k];
    const unsigned short* arp = c1 + (size_t)mrow * 128 + ch;
    const unsigned short* wk = w3t + (size_t)k * 16384;
#pragma unroll
    for (int ccq = 0; ccq < 4; ++ccq) {
      int cc = ccq * 32;
      u16x8 av = {0, 0, 0, 0, 0, 0, 0, 0};
      if (mrow < M) av = *(const u16x8*)(arp + cc);
      *(u16x8*)(sA + r * 40 + ch) = av;
      *(u16x8*)(sB + jb * 40 + chb) = *(const u16x8*)(wk + (size_t)jb * 128 + cc + chb);
      *(u16x8*)(sB + (jb + 64) * 40 + chb) = *(const u16x8*)(wk + (size_t)(jb + 64) * 128 + cc + chb);
      __syncthreads();
      bf16x8 a = __builtin_bit_cast(bf16x8, *(const u16x8*)(sA + aoff));
#pragma unroll
      for (int nb = 0; nb < 8; ++nb) {
        bf16x8 b = __builtin_bit_cast(bf16x8, *(const u16x8*)(sB + boffb + nb * 16 * 40));
        acc[nb] = __builtin_amdgcn_mfma_f32_16x16x32_bf16(a, b, acc[nb], 0, 0, 0);
      }
      __syncthreads();
    }
  }
  int rb = wave * 16 + (lane >> 4) * 4;
  int col = lane & 15;
#pragma unroll
  for (int nb = 0; nb < 8; ++nb) {
    float s = 0.f, q = 0.f;
#pragma unroll
    for (int i = 0; i < 4; ++i) {
      int n = m0 + rb + i;
      unsigned short u = f2bfu(acc[nb][i]);
      if (n < M) c2p[(size_t)n * 128 + nb * 16 + col] = u;
      float v = bfu2f(u);
      s += v; q += v * v;
    }
    s += __shfl_xor(s, 16); s += __shfl_xor(s, 32);
    q += __shfl_xor(q, 16); q += __shfl_xor(q, 32);
    if (lane < 16) {
      sStat[wave][0][nb * 16 + lane] = s;
      sStat[wave][1][nb * 16 + lane] = q;
    }
  }
  __syncthreads();
  if (t < 128) {
    float s = sStat[0][0][t] + sStat[1][0][t] + sStat[2][0][t] + sStat[3][0][t];
    float q = sStat[0][1][t] + sStat[1][1][t] + sStat[2][1][t] + sStat[3][1][t];
    partials[(size_t)blockIdx.x * 256 + t] = s;
    partials[(size_t)blockIdx.x * 256 + 128 + t] = q;
  }
}

// --- reduce partials -> scale/shift, PARALLEL: one block per channel --------
// ss[c] = g*rsqrt(var+eps), ss[C+c] = b - mu*scale
__global__ __launch_bounds__(256) void bn_finalize(
    const float* __restrict__ partials, int nb, int C, int M,
    const float* __restrict__ g, const float* __restrict__ bt,
    float* __restrict__ ss) {
  int c = blockIdx.x;
  int t = threadIdx.x;
  float s = 0.f, s2 = 0.f;
  for (int b = t; b < nb; b += 256) {
    s += partials[(size_t)b * 2 * C + c];
    s2 += partials[(size_t)b * 2 * C + C + c];
  }
#pragma unroll
  for (int off = 32; off >= 1; off >>= 1) {
    s += __shfl_xor(s, off);
    s2 += __shfl_xor(s2, off);
  }
  __shared__ float sh[4][2];
  int wave = t >> 6, lane = t & 63;
  if (lane == 0) { sh[wave][0] = s; sh[wave][1] = s2; }
  __syncthreads();
  if (t == 0) {
    s = sh[0][0] + sh[1][0] + sh[2][0] + sh[3][0];
    s2 = sh[0][1] + sh[1][1] + sh[2][1] + sh[3][1];
    float mean = s / (float)M;
    float var = s2 / (float)M - mean * mean;
    float sc = g[c] * rsqrtf(var + 1e-5f);
    ss[c] = sc;
    ss[C + c] = bt[c] - mean * sc;
  }
}

// --- elementwise BN + ReLU, bf16 in/out -------------------------------------
__global__ __launch_bounds__(256) void bnrelu(
    const unsigned short* __restrict__ P, const float* __restrict__ ss,
    unsigned short* __restrict__ Aout, int total, int Cmask) {
  int i = (blockIdx.x * 256 + threadIdx.x) * 8;
  if (i >= total) return;
  u16x8 v = *(const u16x8*)(P + i);
  int c0 = i & Cmask;
  int C = Cmask + 1;
  u16x8 o;
#pragma unroll
  for (int j = 0; j < 8; ++j) {
    float f = bfu2f(v[j]) * ss[c0 + j] + ss[C + c0 + j];
    o[j] = f2bfu(fmaxf(f, 0.f));
  }
  *(u16x8*)(Aout + i) = o;
}

// --- final: out[c][n] = relu(bn3(c3p) + bnsc(scp)), transposed fp32 write ---
__global__ __launch_bounds__(256) void final_out(
    const unsigned short* __restrict__ c3p, const unsigned short* __restrict__ scp,
    const float* __restrict__ ss3, const float* __restrict__ sssc,
    float* __restrict__ out, int M) {
  __shared__ float tile[64][65];
  int n0 = blockIdx.x * 64, c0 = blockIdx.y * 64;
  int t = threadIdx.x;
  int cl = t & 63;
#pragma unroll
  for (int i = 0; i < 16; ++i) {
    int nl = i * 4 + (t >> 6);
    int n = n0 + nl;
    float v = 0.f;
    if (n < M) {
      int c = c0 + cl;
      float a = bfu2f(c3p[(size_t)n * 512 + c]) * ss3[c] + ss3[512 + c];
      float b = bfu2f(scp[(size_t)n * 512 + c]) * sssc[c] + sssc[512 + c];
      v = fmaxf(a + b, 0.f);
    }
    tile[nl][cl] = v;
  }
  __syncthreads();
  int nl = t & 63;
#pragma unroll
  for (int i = 0; i < 16; ++i) {
    int cl2 = i * 4 + (t >> 6);
    int n = n0 + nl;
    if (n < M) out[(size_t)(c0 + cl2) * M + n0 + nl] = tile[nl][cl2];
  }
}

extern "C" void kernel_launch(void* const* d_in, const int* in_sizes, int n_in,
                              void* d_out, int out_size, void* d_ws, size_t ws_size,
                              hipStream_t stream) {
  const float* x   = (const float*)d_in[0];
  const int* neigh = (const int*)d_in[1];
  const float* W1a = (const float*)d_in[2];
  const float* g1a = (const float*)d_in[3];
  const float* b1a = (const float*)d_in[4];
  const float* W3  = (const float*)d_in[5];
  const float* g3  = (const float*)d_in[6];
  const float* b3  = (const float*)d_in[7];
  const float* W1b = (const float*)d_in[8];
  const float* g1b = (const float*)d_in[9];
  const float* b1b = (const float*)d_in[10];
  const float* Wc  = (const float*)d_in[11];
  const float* gc  = (const float*)d_in[12];
  const float* bc  = (const float*)d_in[13];
  float* out = (float*)d_out;

  const int M = in_sizes[1] / 27;          // 60000 nodes
  const int MT = (M + 63) / 64;            // 938 row tiles

  char* ws = (char*)d_ws;
  unsigned short* h   = (unsigned short*)(ws + 0);           // [M][256] bf16
  unsigned short* wA  = (unsigned short*)(ws + 30720000);    // activations c1/c2 [M][128]
  unsigned short* wP  = (unsigned short*)(ws + 46080000);    // pre-activations [M][128]
  unsigned short* c3p = (unsigned short*)(ws + 61440000);    // [M][512]
  unsigned short* scp = (unsigned short*)(ws + 122880000);   // [M][512]
  unsigned short* w1a = (unsigned short*)(ws + 184320000);   // [128][256]
  unsigned short* w3t = (unsigned short*)(ws + 184385536);   // [27][128][128] d-major
  unsigned short* w1b = (unsigned short*)(ws + 185270272);   // [512][128]
  unsigned short* wc  = (unsigned short*)(ws + 185401344);   // [512][256]
  float* ss1  = (float*)(ws + 185663488);
  float* ss2  = (float*)(ws + 185667584);
  float* ss3  = (float*)(ws + 185671680);
  float* sssc = (float*)(ws + 185679872);

  // Partials live in ws regions that are dead at their point of use:
  float* part12 = (float*)c3p;   // stage-1/2 stats (c3p not yet written)
  float* part3  = (float*)scp;   // stage-3 stats (read by fin3 before gemmsc writes scp)
  float* partsc = (float*)wP;    // shortcut stats (wP dead after bnrelu2)

  prep_weights<<<1728, 256, 0, stream>>>(W1a, W3, W1b, Wc, w1a, w3t, w1b, wc);
  transpose_x<<<dim3(MT, 4), 256, 0, stream>>>(x, h, M);

  const int bnGrid = (M * 128 / 8 + 255) / 256;

  // c1 = relu(bn(h @ W1a^T))
  gemm_bt<<<dim3(MT, 2), 256, 0, stream>>>(h, w1a, wP, part12, M, 256, 128);
  bn_finalize<<<128, 256, 0, stream>>>(part12, MT, 128, M, g1a, b1a, ss1);
  bnrelu<<<bnGrid, 256, 0, stream>>>(wP, ss1, wA, M * 128, 127);

  // c2 = relu(bn(octree_conv(c1)))
  octree_gemm<<<MT, 256, 0, stream>>>(wA, neigh, w3t, wP, part12, M);
  bn_finalize<<<128, 256, 0, stream>>>(part12, MT, 128, M, g3, b3, ss2);
  bnrelu<<<bnGrid, 256, 0, stream>>>(wP, ss2, wA, M * 128, 127);

  // c3_pre = c2 @ W1b^T (stats -> part3, consumed before gemmsc writes scp)
  gemm_bt<<<dim3(MT, 8), 256, 0, stream>>>(wA, w1b, c3p, part3, M, 128, 512);
  bn_finalize<<<512, 256, 0, stream>>>(part3, MT, 512, M, g1b, b1b, ss3);

  // sc_pre = h @ Wc^T
  gemm_bt<<<dim3(MT, 8), 256, 0, stream>>>(h, wc, scp, partsc, M, 256, 512);
  bn_finalize<<<512, 256, 0, stream>>>(partsc, MT, 512, M, gc, bc, sssc);

  // out = relu(bn(c3_pre) + bn(sc_pre)), transposed to [512][M]
  final_out<<<dim3(MT, 8), 256, 0, stream>>>(c3p, scp, ss3, sssc, out, M);
}

// Round 4
// 299.125 us; speedup vs baseline: 4.1157x; 1.1740x over previous
//
#include <hip/hip_runtime.h>

// ---------------------------------------------------------------------------
// OctreeResBlock on MI355X (gfx950), round 3: rebuilt octree_gemm.
// Round-2 profile: octree_gemm 137us @ MfmaUtil 16%, 2.4e7 bank conflicts —
// LDS-instruction-bound (9 ds_read + 3 ds_write per 8 MFMA, 216 barriers).
// New: 128x128 block / 64x64 per-wave tile, global_load_lds(16B) staging with
// XOR-swizzled source + swizzled reads (conflict-free), 54 barriers.
// ---------------------------------------------------------------------------

typedef __bf16 bf16x8 __attribute__((ext_vector_type(8)));
typedef float f32x4 __attribute__((ext_vector_type(4)));
typedef unsigned short u16x8 __attribute__((ext_vector_type(8)));

__device__ __forceinline__ unsigned short f2bfu(float f) {
  union { float f; unsigned u; } v; v.f = f;
  unsigned r = v.u + 0x7fffu + ((v.u >> 16) & 1u);   // round-to-nearest-even
  return (unsigned short)(r >> 16);
}
__device__ __forceinline__ float bfu2f(unsigned short s) {
  union { unsigned u; float f; } v; v.u = ((unsigned)s) << 16;
  return v.f;
}

// async global->LDS, 16B per lane; dest = wave-uniform base + lane*16
__device__ __forceinline__ void gload_lds16(const unsigned short* g, unsigned short* l) {
  __builtin_amdgcn_global_load_lds(
      (const __attribute__((address_space(1))) unsigned int*)(unsigned long long)g,
      (__attribute__((address_space(3))) unsigned int*)(unsigned int)(unsigned long long)l,
      16, 0, 0);
}

// --- weights prep: fp32 -> bf16; W3 [k][c][d] -> w3t [k][d][c] --------------
__global__ __launch_bounds__(256) void prep_weights(
    const float* __restrict__ W1a, const float* __restrict__ W3,
    const float* __restrict__ W1b, const float* __restrict__ Wc,
    unsigned short* __restrict__ w1a, unsigned short* __restrict__ w3t,
    unsigned short* __restrict__ w1b, unsigned short* __restrict__ wc) {
  int i = blockIdx.x * 256 + threadIdx.x;
  int stride = gridDim.x * 256;
  for (; i < 442368; i += stride) {
    if (i < 32768)  w1a[i] = f2bfu(W1a[i]);
    if (i < 65536)  w1b[i] = f2bfu(W1b[i]);
    if (i < 131072) wc[i]  = f2bfu(Wc[i]);
    int k = i >> 14, rr = i & 16383;
    int d = rr >> 7, c = rr & 127;
    w3t[i] = f2bfu(W3[(k << 14) + (c << 7) + d]);
  }
}

// --- x [256][M] fp32 -> h [M][256] bf16 (LDS tile transpose) ----------------
__global__ __launch_bounds__(256) void transpose_x(
    const float* __restrict__ x, unsigned short* __restrict__ h, int M) {
  __shared__ float tile[64][65];
  int n0 = blockIdx.x * 64, c0 = blockIdx.y * 64;
  int t = threadIdx.x;
  int nl = t & 63;
#pragma unroll
  for (int i = 0; i < 16; ++i) {
    int cl = i * 4 + (t >> 6);
    int n = n0 + nl;
    tile[cl][nl] = (n < M) ? x[(size_t)(c0 + cl) * M + n] : 0.f;
  }
  __syncthreads();
  int cl = t & 63;
#pragma unroll
  for (int i = 0; i < 16; ++i) {
    int nl2 = i * 4 + (t >> 6);
    int n = n0 + nl2;
    if (n < M) h[(size_t)n * 256 + c0 + cl] = f2bfu(tile[cl][nl2]);
  }
}

// --- generic GEMM: C[M][Nc] = A[M][Kd] * W[Nc][Kd]^T, all bf16 --------------
__global__ __launch_bounds__(256) void gemm_bt(
    const unsigned short* __restrict__ A, const unsigned short* __restrict__ W,
    unsigned short* __restrict__ C, float* __restrict__ partials,
    int M, int Kd, int Nc) {
  __shared__ unsigned short sA[64 * 40];
  __shared__ unsigned short sB[64 * 40];
  __shared__ float sStat[4][2][64];
  int t = threadIdx.x, wave = t >> 6, lane = t & 63;
  int m0 = blockIdx.x * 64, n0 = blockIdx.y * 64;
  f32x4 acc[4] = {};
  int r = t >> 2, ch = (t & 3) * 8;
  int arow = m0 + r;
  bool aval = arow < M;
  const unsigned short* Ar = A + (size_t)arow * Kd + ch;
  const unsigned short* Wr = W + (size_t)(n0 + r) * Kd + ch;
  int aoff = (wave * 16 + (lane & 15)) * 40 + (lane >> 4) * 8;
  int boffb = (lane & 15) * 40 + (lane >> 4) * 8;
  for (int k0 = 0; k0 < Kd; k0 += 32) {
    u16x8 av = {0, 0, 0, 0, 0, 0, 0, 0};
    if (aval) av = *(const u16x8*)(Ar + k0);
    u16x8 bv = *(const u16x8*)(Wr + k0);
    *(u16x8*)(sA + r * 40 + ch) = av;
    *(u16x8*)(sB + r * 40 + ch) = bv;
    __syncthreads();
    bf16x8 a = __builtin_bit_cast(bf16x8, *(const u16x8*)(sA + aoff));
#pragma unroll
    for (int nb = 0; nb < 4; ++nb) {
      bf16x8 b = __builtin_bit_cast(bf16x8, *(const u16x8*)(sB + boffb + nb * 16 * 40));
      acc[nb] = __builtin_amdgcn_mfma_f32_16x16x32_bf16(a, b, acc[nb], 0, 0, 0);
    }
    __syncthreads();
  }
  int rb = wave * 16 + (lane >> 4) * 4;
  int col = lane & 15;
#pragma unroll
  for (int nb = 0; nb < 4; ++nb) {
    float s = 0.f, q = 0.f;
#pragma unroll
    for (int i = 0; i < 4; ++i) {
      int n = m0 + rb + i;
      unsigned short u = f2bfu(acc[nb][i]);
      if (n < M) C[(size_t)n * Nc + n0 + nb * 16 + col] = u;
      float v = bfu2f(u);
      s += v; q += v * v;
    }
    s += __shfl_xor(s, 16); s += __shfl_xor(s, 32);
    q += __shfl_xor(q, 16); q += __shfl_xor(q, 32);
    if (lane < 16) {
      sStat[wave][0][nb * 16 + lane] = s;
      sStat[wave][1][nb * 16 + lane] = q;
    }
  }
  __syncthreads();
  if (t < 64) {
    float s = sStat[0][0][t] + sStat[1][0][t] + sStat[2][0][t] + sStat[3][0][t];
    float q = sStat[0][1][t] + sStat[1][1][t] + sStat[2][1][t] + sStat[3][1][t];
    partials[(size_t)blockIdx.x * (2 * Nc) + n0 + t] = s;
    partials[(size_t)blockIdx.x * (2 * Nc) + Nc + n0 + t] = q;
  }
}

// --- octree conv: c2p[n][d] = sum_k sum_c c1[neigh[n][k]][c] * w3t[k][d][c] -
// 128x128 block, 4 waves (2Mx2N), 64x64 per wave. global_load_lds staging with
// chunk ^= (row&7) swizzle (inverse-swz source, swz read). c1 has zero row M.
__global__ __launch_bounds__(256) void octree_gemm(
    const unsigned short* __restrict__ c1, const int* __restrict__ neigh,
    const unsigned short* __restrict__ w3t, unsigned short* __restrict__ c2p,
    float* __restrict__ partials, int M) {
  __shared__ unsigned short sA[128 * 128];   // 32 KB, swizzled layout
  __shared__ unsigned short sB[128 * 128];   // 32 KB
  __shared__ unsigned short nidx[128 * 27];  // 6.75 KB (M < 65536)
  __shared__ float sStat[4][2][128];
  int t = threadIdx.x, wave = t >> 6, lane = t & 63;
  int m0 = blockIdx.x * 128;
  for (int i = t; i < 128 * 27; i += 256) {
    int row = i / 27;
    nidx[i] = (unsigned short)((m0 + row < M) ? neigh[(size_t)m0 * 27 + i] : M);
  }
  __syncthreads();

  f32x4 acc[4][4] = {};
  int wr = wave >> 1, wc = wave & 1;
  int l4 = lane >> 4, lc = lane & 15;
  int lc7 = lc & 7;

  for (int k = 0; k < 27; ++k) {
    // stage A: wave stages rows [wave*32, wave*32+32); 4 rows per DMA instr
#pragma unroll
    for (int i = 0; i < 8; ++i) {
      int row = wave * 32 + i * 4 + l4;
      int nr = nidx[row * 27 + k];
      int sc = lc ^ (row & 7);                      // inverse-swizzled source chunk
      gload_lds16(c1 + (size_t)nr * 128 + sc * 8, &sA[(wave * 32 + i * 4) * 128]);
    }
    // stage B: w3t[k] rows [wave*32, wave*32+32)
    const unsigned short* wk = w3t + (size_t)k * 16384;
#pragma unroll
    for (int i = 0; i < 8; ++i) {
      int row = wave * 32 + i * 4 + l4;
      int sc = lc ^ (row & 7);
      gload_lds16(wk + (size_t)row * 128 + sc * 8, &sB[(wave * 32 + i * 4) * 128]);
    }
    __syncthreads();   // drains vmcnt(0) -> all DMA writes visible

    // compute: 4 K-steps of 32 over this k's 128 input channels
#pragma unroll
    for (int kk = 0; kk < 4; ++kk) {
      bf16x8 af[4], bfr[4];
#pragma unroll
      for (int mi = 0; mi < 4; ++mi) {
        int row = wr * 64 + mi * 16 + lc;
        int chunk = (kk * 4 + l4) ^ lc7;            // swizzled read
        af[mi] = __builtin_bit_cast(bf16x8, *(const u16x8*)(sA + row * 128 + chunk * 8));
      }
#pragma unroll
      for (int ni = 0; ni < 4; ++ni) {
        int row = wc * 64 + ni * 16 + lc;
        int chunk = (kk * 4 + l4) ^ lc7;
        bfr[ni] = __builtin_bit_cast(bf16x8, *(const u16x8*)(sB + row * 128 + chunk * 8));
      }
#pragma unroll
      for (int mi = 0; mi < 4; ++mi)
#pragma unroll
        for (int ni = 0; ni < 4; ++ni)
          acc[mi][ni] = __builtin_amdgcn_mfma_f32_16x16x32_bf16(af[mi], bfr[ni], acc[mi][ni], 0, 0, 0);
    }
    __syncthreads();   // reads done before next k's DMA overwrites
  }

  // epilogue: C-write + per-column sum/sumsq
#pragma unroll
  for (int ni = 0; ni < 4; ++ni) {
    float s = 0.f, q = 0.f;
    int col = wc * 64 + ni * 16 + lc;
#pragma unroll
    for (int mi = 0; mi < 4; ++mi)
#pragma unroll
      for (int j = 0; j < 4; ++j) {
        int n = m0 + wr * 64 + mi * 16 + l4 * 4 + j;
        unsigned short u = f2bfu(acc[mi][ni][j]);
        if (n < M) c2p[(size_t)n * 128 + col] = u;
        float v = bfu2f(u);   // rows >= M gathered the zero row -> contribute 0
        s += v; q += v * v;
      }
    s += __shfl_xor(s, 16); s += __shfl_xor(s, 32);
    q += __shfl_xor(q, 16); q += __shfl_xor(q, 32);
    if (lane < 16) {
      sStat[wave][0][col] = s;
      sStat[wave][1][col] = q;
    }
  }
  __syncthreads();
  if (t < 128) {
    int wcs = t >> 6;   // which wave-column covers this channel
    float s = sStat[wcs][0][t] + sStat[wcs + 2][0][t];
    float q = sStat[wcs][1][t] + sStat[wcs + 2][1][t];
    partials[(size_t)blockIdx.x * 256 + t] = s;
    partials[(size_t)blockIdx.x * 256 + 128 + t] = q;
  }
}

// --- reduce partials -> scale/shift, one block per channel ------------------
__global__ __launch_bounds__(256) void bn_finalize(
    const float* __restrict__ partials, int nb, int C, int M,
    const float* __restrict__ g, const float* __restrict__ bt,
    float* __restrict__ ss) {
  int c = blockIdx.x;
  int t = threadIdx.x;
  float s = 0.f, s2 = 0.f;
  for (int b = t; b < nb; b += 256) {
    s += partials[(size_t)b * 2 * C + c];
    s2 += partials[(size_t)b * 2 * C + C + c];
  }
#pragma unroll
  for (int off = 32; off >= 1; off >>= 1) {
    s += __shfl_xor(s, off);
    s2 += __shfl_xor(s2, off);
  }
  __shared__ float sh[4][2];
  int wave = t >> 6, lane = t & 63;
  if (lane == 0) { sh[wave][0] = s; sh[wave][1] = s2; }
  __syncthreads();
  if (t == 0) {
    s = sh[0][0] + sh[1][0] + sh[2][0] + sh[3][0];
    s2 = sh[0][1] + sh[1][1] + sh[2][1] + sh[3][1];
    float mean = s / (float)M;
    float var = s2 / (float)M - mean * mean;
    float sc = g[c] * rsqrtf(var + 1e-5f);
    ss[c] = sc;
    ss[C + c] = bt[c] - mean * sc;
  }
}

// --- elementwise BN + ReLU, bf16 in/out; zero-pads rows [M, Mpad) -----------
__global__ __launch_bounds__(256) void bnrelu(
    const unsigned short* __restrict__ P, const float* __restrict__ ss,
    unsigned short* __restrict__ Aout, int total, int total2, int Cmask) {
  int i = (blockIdx.x * 256 + threadIdx.x) * 8;
  if (i >= total2) return;
  u16x8 o = {0, 0, 0, 0, 0, 0, 0, 0};
  if (i < total) {
    u16x8 v = *(const u16x8*)(P + i);
    int c0 = i & Cmask;
    int C = Cmask + 1;
#pragma unroll
    for (int j = 0; j < 8; ++j) {
      float f = bfu2f(v[j]) * ss[c0 + j] + ss[C + c0 + j];
      o[j] = f2bfu(fmaxf(f, 0.f));
    }
  }
  *(u16x8*)(Aout + i) = o;
}

// --- final: out[c][n] = relu(bn3(c3p) + bnsc(scp)), transposed fp32 write ---
__global__ __launch_bounds__(256) void final_out(
    const unsigned short* __restrict__ c3p, const unsigned short* __restrict__ scp,
    const float* __restrict__ ss3, const float* __restrict__ sssc,
    float* __restrict__ out, int M) {
  __shared__ float tile[64][65];
  int n0 = blockIdx.x * 64, c0 = blockIdx.y * 64;
  int t = threadIdx.x;
  int cl = t & 63;
#pragma unroll
  for (int i = 0; i < 16; ++i) {
    int nl = i * 4 + (t >> 6);
    int n = n0 + nl;
    float v = 0.f;
    if (n < M) {
      int c = c0 + cl;
      float a = bfu2f(c3p[(size_t)n * 512 + c]) * ss3[c] + ss3[512 + c];
      float b = bfu2f(scp[(size_t)n * 512 + c]) * sssc[c] + sssc[512 + c];
      v = fmaxf(a + b, 0.f);
    }
    tile[nl][cl] = v;
  }
  __syncthreads();
  int nl = t & 63;
#pragma unroll
  for (int i = 0; i < 16; ++i) {
    int cl2 = i * 4 + (t >> 6);
    int n = n0 + nl;
    if (n < M) out[(size_t)(c0 + cl2) * M + n0 + nl] = tile[nl][cl2];
  }
}

extern "C" void kernel_launch(void* const* d_in, const int* in_sizes, int n_in,
                              void* d_out, int out_size, void* d_ws, size_t ws_size,
                              hipStream_t stream) {
  const float* x   = (const float*)d_in[0];
  const int* neigh = (const int*)d_in[1];
  const float* W1a = (const float*)d_in[2];
  const float* g1a = (const float*)d_in[3];
  const float* b1a = (const float*)d_in[4];
  const float* W3  = (const float*)d_in[5];
  const float* g3  = (const float*)d_in[6];
  const float* b3  = (const float*)d_in[7];
  const float* W1b = (const float*)d_in[8];
  const float* g1b = (const float*)d_in[9];
  const float* b1b = (const float*)d_in[10];
  const float* Wc  = (const float*)d_in[11];
  const float* gc  = (const float*)d_in[12];
  const float* bc  = (const float*)d_in[13];
  float* out = (float*)d_out;

  const int M = in_sizes[1] / 27;          // 60000 nodes (< 65536: nidx ushort)
  const int MT = (M + 63) / 64;            // 938 row tiles (dense gemms)
  const int MTO = (M + 127) / 128;         // 469 row tiles (octree)

  char* ws = (char*)d_ws;
  unsigned short* h   = (unsigned short*)(ws + 0);           // [M][256] bf16
  unsigned short* wA  = (unsigned short*)(ws + 30720000);    // [M+8][128] (zero-pad rows)
  unsigned short* wP  = (unsigned short*)(ws + 46082048);    // [M][128]
  unsigned short* c3p = (unsigned short*)(ws + 61442048);    // [M][512]
  unsigned short* scp = (unsigned short*)(ws + 122882048);   // [M][512]
  unsigned short* w1a = (unsigned short*)(ws + 184322048);   // [128][256]
  unsigned short* w3t = (unsigned short*)(ws + 184387584);   // [27][128][128] d-major
  unsigned short* w1b = (unsigned short*)(ws + 185272320);   // [512][128]
  unsigned short* wc  = (unsigned short*)(ws + 185403392);   // [512][256]
  float* ss1  = (float*)(ws + 185665536);
  float* ss2  = (float*)(ws + 185669632);
  float* ss3  = (float*)(ws + 185673728);
  float* sssc = (float*)(ws + 185677824);

  // Partials live in ws regions that are dead at their point of use:
  float* part12 = (float*)c3p;   // stage-1/2 stats (c3p not yet written)
  float* part3  = (float*)scp;   // stage-3 stats (read before gemmsc writes scp)
  float* partsc = (float*)wP;    // shortcut stats (wP dead after bnrelu2)

  prep_weights<<<1728, 256, 0, stream>>>(W1a, W3, W1b, Wc, w1a, w3t, w1b, wc);
  transpose_x<<<dim3(MT, 4), 256, 0, stream>>>(x, h, M);

  const int total = M * 128, total2 = (M + 8) * 128;
  const int bnGrid = (total2 / 8 + 255) / 256;

  // c1 = relu(bn(h @ W1a^T))  (wA rows [M, M+8) zeroed for octree gather)
  gemm_bt<<<dim3(MT, 2), 256, 0, stream>>>(h, w1a, wP, part12, M, 256, 128);
  bn_finalize<<<128, 256, 0, stream>>>(part12, MT, 128, M, g1a, b1a, ss1);
  bnrelu<<<bnGrid, 256, 0, stream>>>(wP, ss1, wA, total, total2, 127);

  // c2 = relu(bn(octree_conv(c1)))
  octree_gemm<<<MTO, 256, 0, stream>>>(wA, neigh, w3t, wP, part12, M);
  bn_finalize<<<128, 256, 0, stream>>>(part12, MTO, 128, M, g3, b3, ss2);
  bnrelu<<<bnGrid, 256, 0, stream>>>(wP, ss2, wA, total, total2, 127);

  // c3_pre = c2 @ W1b^T (stats -> part3, consumed before gemmsc writes scp)
  gemm_bt<<<dim3(MT, 8), 256, 0, stream>>>(wA, w1b, c3p, part3, M, 128, 512);
  bn_finalize<<<512, 256, 0, stream>>>(part3, MT, 512, M, g1b, b1b, ss3);

  // sc_pre = h @ Wc^T
  gemm_bt<<<dim3(MT, 8), 256, 0, stream>>>(h, wc, scp, partsc, M, 256, 512);
  bn_finalize<<<512, 256, 0, stream>>>(partsc, MT, 512, M, gc, bc, sssc);

  // out = relu(bn(c3_pre) + bn(sc_pre)), transposed to [512][M]
  final_out<<<dim3(MT, 8), 256, 0, stream>>>(c3p, scp, ss3, sssc, out, M);
}

// Round 5
// 266.116 us; speedup vs baseline: 4.6262x; 1.1240x over previous
//
#include <hip/hip_runtime.h>

// ---------------------------------------------------------------------------
// OctreeResBlock on MI355X (gfx950), round 4:
//  - gemm128: dense GEMMs rebuilt as 128x128 tile, BK=64, global_load_lds(16B)
//    + XOR swizzle + 2-phase LDS double-buffer (stage next | compute cur).
//  - octree_gemm: same 2-phase dbuf across 54 (k,half) phases to overlap the
//    random gather with MFMA (distinguishes drain-stall vs gather-BW floor).
//  - activations padded to Mpad=60032 zero rows -> no per-lane DMA guards.
// ---------------------------------------------------------------------------

typedef __bf16 bf16x8 __attribute__((ext_vector_type(8)));
typedef float f32x4 __attribute__((ext_vector_type(4)));
typedef unsigned short u16x8 __attribute__((ext_vector_type(8)));

__device__ __forceinline__ unsigned short f2bfu(float f) {
  union { float f; unsigned u; } v; v.f = f;
  unsigned r = v.u + 0x7fffu + ((v.u >> 16) & 1u);   // round-to-nearest-even
  return (unsigned short)(r >> 16);
}
__device__ __forceinline__ float bfu2f(unsigned short s) {
  union { unsigned u; float f; } v; v.u = ((unsigned)s) << 16;
  return v.f;
}

// async global->LDS, 16B per lane; dest = wave-uniform base + lane*16
__device__ __forceinline__ void gload_lds16(const unsigned short* g, unsigned short* l) {
  __builtin_amdgcn_global_load_lds(
      (const __attribute__((address_space(1))) unsigned int*)(unsigned long long)g,
      (__attribute__((address_space(3))) unsigned int*)(unsigned int)(unsigned long long)l,
      16, 0, 0);
}

// --- weights prep: fp32 -> bf16; W3 [k][c][d] -> w3t [k][d][c] --------------
__global__ __launch_bounds__(256) void prep_weights(
    const float* __restrict__ W1a, const float* __restrict__ W3,
    const float* __restrict__ W1b, const float* __restrict__ Wc,
    unsigned short* __restrict__ w1a, unsigned short* __restrict__ w3t,
    unsigned short* __restrict__ w1b, unsigned short* __restrict__ wc) {
  int i = blockIdx.x * 256 + threadIdx.x;
  int stride = gridDim.x * 256;
  for (; i < 442368; i += stride) {
    if (i < 32768)  w1a[i] = f2bfu(W1a[i]);
    if (i < 65536)  w1b[i] = f2bfu(W1b[i]);
    if (i < 131072) wc[i]  = f2bfu(Wc[i]);
    int k = i >> 14, rr = i & 16383;
    int d = rr >> 7, c = rr & 127;
    w3t[i] = f2bfu(W3[(k << 14) + (c << 7) + d]);
  }
}

// --- x [256][M] fp32 -> h [Mpad][256] bf16 (zero rows beyond M) -------------
__global__ __launch_bounds__(256) void transpose_x(
    const float* __restrict__ x, unsigned short* __restrict__ h, int M) {
  __shared__ float tile[64][65];
  int n0 = blockIdx.x * 64, c0 = blockIdx.y * 64;
  int t = threadIdx.x;
  int nl = t & 63;
#pragma unroll
  for (int i = 0; i < 16; ++i) {
    int cl = i * 4 + (t >> 6);
    int n = n0 + nl;
    tile[cl][nl] = (n < M) ? x[(size_t)(c0 + cl) * M + n] : 0.f;
  }
  __syncthreads();
  int cl = t & 63;
#pragma unroll
  for (int i = 0; i < 16; ++i) {
    int nl2 = i * 4 + (t >> 6);
    int n = n0 + nl2;
    h[(size_t)n * 256 + c0 + cl] = f2bfu(tile[cl][nl2]);   // pad rows get zeros
  }
}

// --- dense GEMM: C[M][Nc] = A[Mpad][Kd] * W[Nc][Kd]^T -----------------------
// 128x128 tile, 4 waves (2x2), BK=64, gload_lds + swizzle, 2-phase dbuf.
// grid = (Nc/128, MTO): col-tiles fastest so A-row-tile is shared in L2.
__global__ __launch_bounds__(256) void gemm128(
    const unsigned short* __restrict__ A, const unsigned short* __restrict__ W,
    unsigned short* __restrict__ C, float* __restrict__ partials,
    int M, int Kd, int Nc) {
  __shared__ unsigned short sA[2][128 * 64];
  __shared__ unsigned short sB[2][128 * 64];
  __shared__ float sStat[4][2][128];
  int t = threadIdx.x, wave = t >> 6, lane = t & 63;
  int n0 = blockIdx.x * 128, m0 = blockIdx.y * 128;
  int wr = wave >> 1, wcc = wave & 1;
  int l4 = lane >> 4, lc = lane & 15, lc7 = lc & 7;
  int lrow = lane >> 3, lch = lane & 7;
  f32x4 acc[4][4] = {};
  const int np = Kd >> 6;

  auto STAGE = [&](int p, int buf) {
    int k0 = p << 6;
#pragma unroll
    for (int i = 0; i < 4; ++i) {
      int row = wave * 32 + i * 8 + lrow;
      int sc = lch ^ (row & 7);
      gload_lds16(A + (size_t)(m0 + row) * Kd + k0 + sc * 8, &sA[buf][(wave * 32 + i * 8) * 64]);
    }
#pragma unroll
    for (int i = 0; i < 4; ++i) {
      int row = wave * 32 + i * 8 + lrow;
      int sc = lch ^ (row & 7);
      gload_lds16(W + (size_t)(n0 + row) * Kd + k0 + sc * 8, &sB[buf][(wave * 32 + i * 8) * 64]);
    }
  };
  auto COMPUTE = [&](int buf) {
#pragma unroll
    for (int kk = 0; kk < 2; ++kk) {
      bf16x8 af[4], bfr[4];
#pragma unroll
      for (int mi = 0; mi < 4; ++mi) {
        int row = wr * 64 + mi * 16 + lc;
        int chunk = (kk * 4 + l4) ^ lc7;
        af[mi] = __builtin_bit_cast(bf16x8, *(const u16x8*)(&sA[buf][row * 64 + chunk * 8]));
      }
#pragma unroll
      for (int ni = 0; ni < 4; ++ni) {
        int row = wcc * 64 + ni * 16 + lc;
        int chunk = (kk * 4 + l4) ^ lc7;
        bfr[ni] = __builtin_bit_cast(bf16x8, *(const u16x8*)(&sB[buf][row * 64 + chunk * 8]));
      }
#pragma unroll
      for (int mi = 0; mi < 4; ++mi)
#pragma unroll
        for (int ni = 0; ni < 4; ++ni)
          acc[mi][ni] = __builtin_amdgcn_mfma_f32_16x16x32_bf16(af[mi], bfr[ni], acc[mi][ni], 0, 0, 0);
    }
  };

  STAGE(0, 0);
  __syncthreads();
  int cur = 0;
  for (int p = 0; p < np - 1; ++p) {
    STAGE(p + 1, cur ^ 1);   // buf cur^1: all waves done reading it (prev barrier)
    COMPUTE(cur);
    __syncthreads();          // drains vmcnt -> next phase data visible
    cur ^= 1;
  }
  COMPUTE(cur);

  // epilogue: C-write + per-column sum/sumsq partials
#pragma unroll
  for (int ni = 0; ni < 4; ++ni) {
    float s = 0.f, q = 0.f;
    int col = wcc * 64 + ni * 16 + lc;
#pragma unroll
    for (int mi = 0; mi < 4; ++mi)
#pragma unroll
      for (int j = 0; j < 4; ++j) {
        int n = m0 + wr * 64 + mi * 16 + l4 * 4 + j;
        unsigned short u = f2bfu(acc[mi][ni][j]);
        if (n < M) C[(size_t)n * Nc + n0 + col] = u;
        float v = bfu2f(u);   // pad rows have zero A -> contribute 0
        s += v; q += v * v;
      }
    s += __shfl_xor(s, 16); s += __shfl_xor(s, 32);
    q += __shfl_xor(q, 16); q += __shfl_xor(q, 32);
    if (lane < 16) {
      sStat[wave][0][col] = s;
      sStat[wave][1][col] = q;
    }
  }
  __syncthreads();
  if (t < 128) {
    int wcs = t >> 6;
    float s = sStat[wcs][0][t] + sStat[wcs + 2][0][t];
    float q = sStat[wcs][1][t] + sStat[wcs + 2][1][t];
    partials[(size_t)blockIdx.y * (2 * Nc) + n0 + t] = s;
    partials[(size_t)blockIdx.y * (2 * Nc) + Nc + n0 + t] = q;
  }
}

// --- octree conv: c2p[n][d] = sum_k sum_c c1[neigh[n][k]][c] * w3t[k][d][c] -
// 128x128 block, BK=64, 54 (k,half) phases, 2-phase dbuf over gather DMA.
__global__ __launch_bounds__(256) void octree_gemm(
    const unsigned short* __restrict__ c1, const int* __restrict__ neigh,
    const unsigned short* __restrict__ w3t, unsigned short* __restrict__ c2p,
    float* __restrict__ partials, int M) {
  __shared__ unsigned short sA[2][128 * 64];
  __shared__ unsigned short sB[2][128 * 64];
  __shared__ unsigned short nidx[128 * 27];  // M < 65536
  __shared__ float sStat[4][2][128];
  int t = threadIdx.x, wave = t >> 6, lane = t & 63;
  int m0 = blockIdx.x * 128;
  for (int i = t; i < 128 * 27; i += 256) {
    int row = i / 27;
    nidx[i] = (unsigned short)((m0 + row < M) ? neigh[(size_t)m0 * 27 + i] : M);
  }
  __syncthreads();

  int wr = wave >> 1, wcc = wave & 1;
  int l4 = lane >> 4, lc = lane & 15, lc7 = lc & 7;
  int lrow = lane >> 3, lch = lane & 7;
  f32x4 acc[4][4] = {};

  auto STAGE = [&](int p, int buf) {
    int k = p >> 1, c0 = (p & 1) << 6;
#pragma unroll
    for (int i = 0; i < 4; ++i) {
      int row = wave * 32 + i * 8 + lrow;
      int nr = nidx[row * 27 + k];
      int sc = lch ^ (row & 7);
      gload_lds16(c1 + ((size_t)nr << 7) + c0 + sc * 8, &sA[buf][(wave * 32 + i * 8) * 64]);
    }
    const unsigned short* wk = w3t + ((size_t)k << 14);
#pragma unroll
    for (int i = 0; i < 4; ++i) {
      int row = wave * 32 + i * 8 + lrow;
      int sc = lch ^ (row & 7);
      gload_lds16(wk + ((size_t)row << 7) + c0 + sc * 8, &sB[buf][(wave * 32 + i * 8) * 64]);
    }
  };
  auto COMPUTE = [&](int buf) {
#pragma unroll
    for (int kk = 0; kk < 2; ++kk) {
      bf16x8 af[4], bfr[4];
#pragma unroll
      for (int mi = 0; mi < 4; ++mi) {
        int row = wr * 64 + mi * 16 + lc;
        int chunk = (kk * 4 + l4) ^ lc7;
        af[mi] = __builtin_bit_cast(bf16x8, *(const u16x8*)(&sA[buf][row * 64 + chunk * 8]));
      }
#pragma unroll
      for (int ni = 0; ni < 4; ++ni) {
        int row = wcc * 64 + ni * 16 + lc;
        int chunk = (kk * 4 + l4) ^ lc7;
        bfr[ni] = __builtin_bit_cast(bf16x8, *(const u16x8*)(&sB[buf][row * 64 + chunk * 8]));
      }
#pragma unroll
      for (int mi = 0; mi < 4; ++mi)
#pragma unroll
        for (int ni = 0; ni < 4; ++ni)
          acc[mi][ni] = __builtin_amdgcn_mfma_f32_16x16x32_bf16(af[mi], bfr[ni], acc[mi][ni], 0, 0, 0);
    }
  };

  STAGE(0, 0);
  __syncthreads();
  int cur = 0;
  for (int p = 0; p < 53; ++p) {
    STAGE(p + 1, cur ^ 1);
    COMPUTE(cur);
    __syncthreads();
    cur ^= 1;
  }
  COMPUTE(cur);

#pragma unroll
  for (int ni = 0; ni < 4; ++ni) {
    float s = 0.f, q = 0.f;
    int col = wcc * 64 + ni * 16 + lc;
#pragma unroll
    for (int mi = 0; mi < 4; ++mi)
#pragma unroll
      for (int j = 0; j < 4; ++j) {
        int n = m0 + wr * 64 + mi * 16 + l4 * 4 + j;
        unsigned short u = f2bfu(acc[mi][ni][j]);
        if (n < M) c2p[(size_t)n * 128 + col] = u;
        float v = bfu2f(u);   // rows >= M gathered the zero row -> contribute 0
        s += v; q += v * v;
      }
    s += __shfl_xor(s, 16); s += __shfl_xor(s, 32);
    q += __shfl_xor(q, 16); q += __shfl_xor(q, 32);
    if (lane < 16) {
      sStat[wave][0][col] = s;
      sStat[wave][1][col] = q;
    }
  }
  __syncthreads();
  if (t < 128) {
    int wcs = t >> 6;
    float s = sStat[wcs][0][t] + sStat[wcs + 2][0][t];
    float q = sStat[wcs][1][t] + sStat[wcs + 2][1][t];
    partials[(size_t)blockIdx.x * 256 + t] = s;
    partials[(size_t)blockIdx.x * 256 + 128 + t] = q;
  }
}

// --- reduce partials -> scale/shift, one block per channel ------------------
__global__ __launch_bounds__(256) void bn_finalize(
    const float* __restrict__ partials, int nb, int C, int M,
    const float* __restrict__ g, const float* __restrict__ bt,
    float* __restrict__ ss) {
  int c = blockIdx.x;
  int t = threadIdx.x;
  float s = 0.f, s2 = 0.f;
  for (int b = t; b < nb; b += 256) {
    s += partials[(size_t)b * 2 * C + c];
    s2 += partials[(size_t)b * 2 * C + C + c];
  }
#pragma unroll
  for (int off = 32; off >= 1; off >>= 1) {
    s += __shfl_xor(s, off);
    s2 += __shfl_xor(s2, off);
  }
  __shared__ float sh[4][2];
  int wave = t >> 6, lane = t & 63;
  if (lane == 0) { sh[wave][0] = s; sh[wave][1] = s2; }
  __syncthreads();
  if (t == 0) {
    s = sh[0][0] + sh[1][0] + sh[2][0] + sh[3][0];
    s2 = sh[0][1] + sh[1][1] + sh[2][1] + sh[3][1];
    float mean = s / (float)M;
    float var = s2 / (float)M - mean * mean;
    float sc = g[c] * rsqrtf(var + 1e-5f);
    ss[c] = sc;
    ss[C + c] = bt[c] - mean * sc;
  }
}

// --- elementwise BN + ReLU, bf16 in/out; zero-pads rows [M, Mpad) -----------
__global__ __launch_bounds__(256) void bnrelu(
    const unsigned short* __restrict__ P, const float* __restrict__ ss,
    unsigned short* __restrict__ Aout, int total, int total2, int Cmask) {
  int i = (blockIdx.x * 256 + threadIdx.x) * 8;
  if (i >= total2) return;
  u16x8 o = {0, 0, 0, 0, 0, 0, 0, 0};
  if (i < total) {
    u16x8 v = *(const u16x8*)(P + i);
    int c0 = i & Cmask;
    int C = Cmask + 1;
#pragma unroll
    for (int j = 0; j < 8; ++j) {
      float f = bfu2f(v[j]) * ss[c0 + j] + ss[C + c0 + j];
      o[j] = f2bfu(fmaxf(f, 0.f));
    }
  }
  *(u16x8*)(Aout + i) = o;
}

// --- final: out[c][n] = relu(bn3(c3p) + bnsc(scp)), transposed fp32 write ---
__global__ __launch_bounds__(256) void final_out(
    const unsigned short* __restrict__ c3p, const unsigned short* __restrict__ scp,
    const float* __restrict__ ss3, const float* __restrict__ sssc,
    float* __restrict__ out, int M) {
  __shared__ float tile[64][65];
  int n0 = blockIdx.x * 64, c0 = blockIdx.y * 64;
  int t = threadIdx.x;
  int cl = t & 63;
#pragma unroll
  for (int i = 0; i < 16; ++i) {
    int nl = i * 4 + (t >> 6);
    int n = n0 + nl;
    float v = 0.f;
    if (n < M) {
      int c = c0 + cl;
      float a = bfu2f(c3p[(size_t)n * 512 + c]) * ss3[c] + ss3[512 + c];
      float b = bfu2f(scp[(size_t)n * 512 + c]) * sssc[c] + sssc[512 + c];
      v = fmaxf(a + b, 0.f);
    }
    tile[nl][cl] = v;
  }
  __syncthreads();
  int nl = t & 63;
#pragma unroll
  for (int i = 0; i < 16; ++i) {
    int cl2 = i * 4 + (t >> 6);
    int n = n0 + nl;
    if (n < M) out[(size_t)(c0 + cl2) * M + n0 + nl] = tile[nl][cl2];
  }
}

extern "C" void kernel_launch(void* const* d_in, const int* in_sizes, int n_in,
                              void* d_out, int out_size, void* d_ws, size_t ws_size,
                              hipStream_t stream) {
  const float* x   = (const float*)d_in[0];
  const int* neigh = (const int*)d_in[1];
  const float* W1a = (const float*)d_in[2];
  const float* g1a = (const float*)d_in[3];
  const float* b1a = (const float*)d_in[4];
  const float* W3  = (const float*)d_in[5];
  const float* g3  = (const float*)d_in[6];
  const float* b3  = (const float*)d_in[7];
  const float* W1b = (const float*)d_in[8];
  const float* g1b = (const float*)d_in[9];
  const float* b1b = (const float*)d_in[10];
  const float* Wc  = (const float*)d_in[11];
  const float* gc  = (const float*)d_in[12];
  const float* bc  = (const float*)d_in[13];
  float* out = (float*)d_out;

  const int M = in_sizes[1] / 27;          // 60000 nodes (< 65536: nidx ushort)
  const int MT = (M + 63) / 64;            // 938 (transpose/final tiles)
  const int MTO = (M + 127) / 128;         // 469 (GEMM row tiles)
  // Mpad = MT*64 = MTO*128 = 60032

  char* ws = (char*)d_ws;
  unsigned short* h   = (unsigned short*)(ws + 0);           // [60032][256] bf16
  unsigned short* wA  = (unsigned short*)(ws + 30736384);    // [60032][128]
  unsigned short* wP  = (unsigned short*)(ws + 46104576);    // [M][128]
  unsigned short* c3p = (unsigned short*)(ws + 61464576);    // [M][512]
  unsigned short* scp = (unsigned short*)(ws + 122904576);   // [M][512]
  unsigned short* w1a = (unsigned short*)(ws + 184344576);   // [128][256]
  unsigned short* w3t = (unsigned short*)(ws + 184410112);   // [27][128][128] d-major
  unsigned short* w1b = (unsigned short*)(ws + 185294848);   // [512][128]
  unsigned short* wc  = (unsigned short*)(ws + 185425920);   // [512][256]
  float* ss1  = (float*)(ws + 185688064);
  float* ss2  = (float*)(ws + 185692160);
  float* ss3  = (float*)(ws + 185696256);
  float* sssc = (float*)(ws + 185700352);

  // Partials live in ws regions that are dead at their point of use:
  float* part12 = (float*)c3p;   // stage-1/2 stats (c3p not yet written)
  float* part3  = (float*)scp;   // stage-3 stats (read before gemmsc writes scp)
  float* partsc = (float*)wP;    // shortcut stats (wP dead after bnrelu2)

  prep_weights<<<1728, 256, 0, stream>>>(W1a, W3, W1b, Wc, w1a, w3t, w1b, wc);
  transpose_x<<<dim3(MT, 4), 256, 0, stream>>>(x, h, M);

  const int total = M * 128, total2 = (MT * 64) * 128;
  const int bnGrid = (total2 / 8 + 255) / 256;

  // c1 = relu(bn(h @ W1a^T))   (wA pad rows zeroed for octree gather)
  gemm128<<<dim3(1, MTO), 256, 0, stream>>>(h, w1a, wP, part12, M, 256, 128);
  bn_finalize<<<128, 256, 0, stream>>>(part12, MTO, 128, M, g1a, b1a, ss1);
  bnrelu<<<bnGrid, 256, 0, stream>>>(wP, ss1, wA, total, total2, 127);

  // c2 = relu(bn(octree_conv(c1)))
  octree_gemm<<<MTO, 256, 0, stream>>>(wA, neigh, w3t, wP, part12, M);
  bn_finalize<<<128, 256, 0, stream>>>(part12, MTO, 128, M, g3, b3, ss2);
  bnrelu<<<bnGrid, 256, 0, stream>>>(wP, ss2, wA, total, total2, 127);

  // c3_pre = c2 @ W1b^T (stats -> part3, consumed before gemmsc writes scp)
  gemm128<<<dim3(4, MTO), 256, 0, stream>>>(wA, w1b, c3p, part3, M, 128, 512);
  bn_finalize<<<512, 256, 0, stream>>>(part3, MTO, 512, M, g1b, b1b, ss3);

  // sc_pre = h @ Wc^T
  gemm128<<<dim3(4, MTO), 256, 0, stream>>>(h, wc, scp, partsc, M, 256, 512);
  bn_finalize<<<512, 256, 0, stream>>>(partsc, MTO, 512, M, gc, bc, sssc);

  // out = relu(bn(c3_pre) + bn(sc_pre)), transposed to [512][M]
  final_out<<<dim3(MT, 8), 256, 0, stream>>>(c3p, scp, ss3, sssc, out, M);
}

// Round 6
// 253.725 us; speedup vs baseline: 4.8522x; 1.0488x over previous
//
#include <hip/hip_runtime.h>

// ---------------------------------------------------------------------------
// OctreeResBlock on MI355X (gfx950), round 5:
// octree_gemm rebuilt for latency hiding — round-5 profile showed the "dbuf"
// was a placebo (__syncthreads drains vmcnt(0), serializing every gather).
// Now: raw s_barrier + counted s_waitcnt vmcnt(4) (next phase's 4 DMAs stay
// in flight across barriers), 512-thread blocks (16 waves/CU vs 8), nidx/stat
// LDS union (72KB -> still 2 blocks/CU), setprio around MFMA cluster.
// Dense gemm128 unchanged (isolate the experiment).
// ---------------------------------------------------------------------------

typedef __bf16 bf16x8 __attribute__((ext_vector_type(8)));
typedef float f32x4 __attribute__((ext_vector_type(4)));
typedef unsigned short u16x8 __attribute__((ext_vector_type(8)));

__device__ __forceinline__ unsigned short f2bfu(float f) {
  union { float f; unsigned u; } v; v.f = f;
  unsigned r = v.u + 0x7fffu + ((v.u >> 16) & 1u);   // round-to-nearest-even
  return (unsigned short)(r >> 16);
}
__device__ __forceinline__ float bfu2f(unsigned short s) {
  union { unsigned u; float f; } v; v.u = ((unsigned)s) << 16;
  return v.f;
}

// async global->LDS, 16B per lane; dest = wave-uniform base + lane*16
__device__ __forceinline__ void gload_lds16(const unsigned short* g, unsigned short* l) {
  __builtin_amdgcn_global_load_lds(
      (const __attribute__((address_space(1))) unsigned int*)(unsigned long long)g,
      (__attribute__((address_space(3))) unsigned int*)(unsigned int)(unsigned long long)l,
      16, 0, 0);
}

// --- weights prep: fp32 -> bf16; W3 [k][c][d] -> w3t [k][d][c] --------------
__global__ __launch_bounds__(256) void prep_weights(
    const float* __restrict__ W1a, const float* __restrict__ W3,
    const float* __restrict__ W1b, const float* __restrict__ Wc,
    unsigned short* __restrict__ w1a, unsigned short* __restrict__ w3t,
    unsigned short* __restrict__ w1b, unsigned short* __restrict__ wc) {
  int i = blockIdx.x * 256 + threadIdx.x;
  int stride = gridDim.x * 256;
  for (; i < 442368; i += stride) {
    if (i < 32768)  w1a[i] = f2bfu(W1a[i]);
    if (i < 65536)  w1b[i] = f2bfu(W1b[i]);
    if (i < 131072) wc[i]  = f2bfu(Wc[i]);
    int k = i >> 14, rr = i & 16383;
    int d = rr >> 7, c = rr & 127;
    w3t[i] = f2bfu(W3[(k << 14) + (c << 7) + d]);
  }
}

// --- x [256][M] fp32 -> h [Mpad][256] bf16 (zero rows beyond M) -------------
__global__ __launch_bounds__(256) void transpose_x(
    const float* __restrict__ x, unsigned short* __restrict__ h, int M) {
  __shared__ float tile[64][65];
  int n0 = blockIdx.x * 64, c0 = blockIdx.y * 64;
  int t = threadIdx.x;
  int nl = t & 63;
#pragma unroll
  for (int i = 0; i < 16; ++i) {
    int cl = i * 4 + (t >> 6);
    int n = n0 + nl;
    tile[cl][nl] = (n < M) ? x[(size_t)(c0 + cl) * M + n] : 0.f;
  }
  __syncthreads();
  int cl = t & 63;
#pragma unroll
  for (int i = 0; i < 16; ++i) {
    int nl2 = i * 4 + (t >> 6);
    int n = n0 + nl2;
    h[(size_t)n * 256 + c0 + cl] = f2bfu(tile[cl][nl2]);   // pad rows get zeros
  }
}

// --- dense GEMM: C[M][Nc] = A[Mpad][Kd] * W[Nc][Kd]^T (unchanged r4) --------
__global__ __launch_bounds__(256) void gemm128(
    const unsigned short* __restrict__ A, const unsigned short* __restrict__ W,
    unsigned short* __restrict__ C, float* __restrict__ partials,
    int M, int Kd, int Nc) {
  __shared__ unsigned short sA[2][128 * 64];
  __shared__ unsigned short sB[2][128 * 64];
  __shared__ float sStat[4][2][128];
  int t = threadIdx.x, wave = t >> 6, lane = t & 63;
  int n0 = blockIdx.x * 128, m0 = blockIdx.y * 128;
  int wr = wave >> 1, wcc = wave & 1;
  int l4 = lane >> 4, lc = lane & 15, lc7 = lc & 7;
  int lrow = lane >> 3, lch = lane & 7;
  f32x4 acc[4][4] = {};
  const int np = Kd >> 6;

  auto STAGE = [&](int p, int buf) {
    int k0 = p << 6;
#pragma unroll
    for (int i = 0; i < 4; ++i) {
      int row = wave * 32 + i * 8 + lrow;
      int sc = lch ^ (row & 7);
      gload_lds16(A + (size_t)(m0 + row) * Kd + k0 + sc * 8, &sA[buf][(wave * 32 + i * 8) * 64]);
    }
#pragma unroll
    for (int i = 0; i < 4; ++i) {
      int row = wave * 32 + i * 8 + lrow;
      int sc = lch ^ (row & 7);
      gload_lds16(W + (size_t)(n0 + row) * Kd + k0 + sc * 8, &sB[buf][(wave * 32 + i * 8) * 64]);
    }
  };
  auto COMPUTE = [&](int buf) {
#pragma unroll
    for (int kk = 0; kk < 2; ++kk) {
      bf16x8 af[4], bfr[4];
#pragma unroll
      for (int mi = 0; mi < 4; ++mi) {
        int row = wr * 64 + mi * 16 + lc;
        int chunk = (kk * 4 + l4) ^ lc7;
        af[mi] = __builtin_bit_cast(bf16x8, *(const u16x8*)(&sA[buf][row * 64 + chunk * 8]));
      }
#pragma unroll
      for (int ni = 0; ni < 4; ++ni) {
        int row = wcc * 64 + ni * 16 + lc;
        int chunk = (kk * 4 + l4) ^ lc7;
        bfr[ni] = __builtin_bit_cast(bf16x8, *(const u16x8*)(&sB[buf][row * 64 + chunk * 8]));
      }
#pragma unroll
      for (int mi = 0; mi < 4; ++mi)
#pragma unroll
        for (int ni = 0; ni < 4; ++ni)
          acc[mi][ni] = __builtin_amdgcn_mfma_f32_16x16x32_bf16(af[mi], bfr[ni], acc[mi][ni], 0, 0, 0);
    }
  };

  STAGE(0, 0);
  __syncthreads();
  int cur = 0;
  for (int p = 0; p < np - 1; ++p) {
    STAGE(p + 1, cur ^ 1);
    COMPUTE(cur);
    __syncthreads();
    cur ^= 1;
  }
  COMPUTE(cur);

#pragma unroll
  for (int ni = 0; ni < 4; ++ni) {
    float s = 0.f, q = 0.f;
    int col = wcc * 64 + ni * 16 + lc;
#pragma unroll
    for (int mi = 0; mi < 4; ++mi)
#pragma unroll
      for (int j = 0; j < 4; ++j) {
        int n = m0 + wr * 64 + mi * 16 + l4 * 4 + j;
        unsigned short u = f2bfu(acc[mi][ni][j]);
        if (n < M) C[(size_t)n * Nc + n0 + col] = u;
        float v = bfu2f(u);
        s += v; q += v * v;
      }
    s += __shfl_xor(s, 16); s += __shfl_xor(s, 32);
    q += __shfl_xor(q, 16); q += __shfl_xor(q, 32);
    if (lane < 16) {
      sStat[wave][0][col] = s;
      sStat[wave][1][col] = q;
    }
  }
  __syncthreads();
  if (t < 128) {
    int wcs = t >> 6;
    float s = sStat[wcs][0][t] + sStat[wcs + 2][0][t];
    float q = sStat[wcs][1][t] + sStat[wcs + 2][1][t];
    partials[(size_t)blockIdx.y * (2 * Nc) + n0 + t] = s;
    partials[(size_t)blockIdx.y * (2 * Nc) + Nc + n0 + t] = q;
  }
}

// --- octree conv: c2p[n][d] = sum_k sum_c c1[neigh[n][k]][c] * w3t[k][d][c] -
// 128x128 block, 512 threads (8 waves, 4x2), BK=64, 54 phases.
// Counted-vmcnt pipeline: next phase's 4 DMAs stay in flight across barriers.
__global__ __launch_bounds__(512, 4) void octree_gemm(
    const unsigned short* __restrict__ c1, const int* __restrict__ neigh,
    const unsigned short* __restrict__ w3t, unsigned short* __restrict__ c2p,
    float* __restrict__ partials, int M) {
  __shared__ unsigned short sA[2][128 * 64];   // 32 KB
  __shared__ unsigned short sB[2][128 * 64];   // 32 KB
  __shared__ union {
    unsigned short nidx[128 * 27];             // main loop (M < 65536)
    float stat[8][2][128];                     // epilogue only
  } u;                                          // 8 KB -> total 72 KB, 2 blk/CU
  int t = threadIdx.x, wave = t >> 6, lane = t & 63;
  int m0 = blockIdx.x * 128;
  for (int i = t; i < 128 * 27; i += 512) {
    int row = i / 27;
    u.nidx[i] = (unsigned short)((m0 + row < M) ? neigh[(size_t)m0 * 27 + i] : M);
  }
  __syncthreads();

  int wr = wave >> 1, wcc = wave & 1;
  int l4 = lane >> 4, lc = lane & 15, lc7 = lc & 7;
  int lrow = lane >> 3, lch = lane & 7;
  f32x4 acc[2][4] = {};

  // per wave: 16 A-rows + 16 B-rows per phase = 4 DMA instrs (2+2)
  auto STAGE = [&](int p, int buf) {
    int k = p >> 1, c0 = (p & 1) << 6;
#pragma unroll
    for (int i = 0; i < 2; ++i) {
      int row = wave * 16 + i * 8 + lrow;
      int nr = u.nidx[row * 27 + k];
      int sc = lch ^ (row & 7);
      gload_lds16(c1 + ((size_t)nr << 7) + c0 + sc * 8, &sA[buf][(wave * 16 + i * 8) * 64]);
    }
    const unsigned short* wk = w3t + ((size_t)k << 14);
#pragma unroll
    for (int i = 0; i < 2; ++i) {
      int row = wave * 16 + i * 8 + lrow;
      int sc = lch ^ (row & 7);
      gload_lds16(wk + ((size_t)row << 7) + c0 + sc * 8, &sB[buf][(wave * 16 + i * 8) * 64]);
    }
  };
  auto COMPUTE = [&](int buf) {
#pragma unroll
    for (int kk = 0; kk < 2; ++kk) {
      bf16x8 af[2], bfr[4];
#pragma unroll
      for (int mi = 0; mi < 2; ++mi) {
        int row = wr * 32 + mi * 16 + lc;
        int chunk = (kk * 4 + l4) ^ lc7;
        af[mi] = __builtin_bit_cast(bf16x8, *(const u16x8*)(&sA[buf][row * 64 + chunk * 8]));
      }
#pragma unroll
      for (int ni = 0; ni < 4; ++ni) {
        int row = wcc * 64 + ni * 16 + lc;
        int chunk = (kk * 4 + l4) ^ lc7;
        bfr[ni] = __builtin_bit_cast(bf16x8, *(const u16x8*)(&sB[buf][row * 64 + chunk * 8]));
      }
      __builtin_amdgcn_s_setprio(1);
#pragma unroll
      for (int mi = 0; mi < 2; ++mi)
#pragma unroll
        for (int ni = 0; ni < 4; ++ni)
          acc[mi][ni] = __builtin_amdgcn_mfma_f32_16x16x32_bf16(af[mi], bfr[ni], acc[mi][ni], 0, 0, 0);
      __builtin_amdgcn_s_setprio(0);
    }
  };

  STAGE(0, 0);
  for (int p = 0; p < 54; ++p) {
    int cur = p & 1;
    if (p < 53) {
      STAGE(p + 1, cur ^ 1);
      asm volatile("s_waitcnt vmcnt(4)" ::: "memory");   // own cur-stage done
    } else {
      asm volatile("s_waitcnt vmcnt(0)" ::: "memory");
    }
    __builtin_amdgcn_sched_barrier(0);
    __builtin_amdgcn_s_barrier();                         // raw: no vmcnt drain
    __builtin_amdgcn_sched_barrier(0);
    COMPUTE(cur);
    __builtin_amdgcn_sched_barrier(0);                    // pin ds_reads above
    __builtin_amdgcn_s_barrier();                         // cur readable until here
  }

  // epilogue: C-write + per-column sum/sumsq (u.nidx dead -> u.stat live)
#pragma unroll
  for (int ni = 0; ni < 4; ++ni) {
    float s = 0.f, q = 0.f;
    int col = wcc * 64 + ni * 16 + lc;
#pragma unroll
    for (int mi = 0; mi < 2; ++mi)
#pragma unroll
      for (int j = 0; j < 4; ++j) {
        int n = m0 + wr * 32 + mi * 16 + l4 * 4 + j;
        unsigned short uo = f2bfu(acc[mi][ni][j]);
        if (n < M) c2p[(size_t)n * 128 + col] = uo;
        float v = bfu2f(uo);   // rows >= M gathered the zero row -> contribute 0
        s += v; q += v * v;
      }
    s += __shfl_xor(s, 16); s += __shfl_xor(s, 32);
    q += __shfl_xor(q, 16); q += __shfl_xor(q, 32);
    if (lane < 16) {
      u.stat[wave][0][col] = s;
      u.stat[wave][1][col] = q;
    }
  }
  __syncthreads();
  if (t < 128) {
    int wcs = t >> 6;
    float s = 0.f, q = 0.f;
#pragma unroll
    for (int g = 0; g < 4; ++g) {
      s += u.stat[g * 2 + wcs][0][t];
      q += u.stat[g * 2 + wcs][1][t];
    }
    partials[(size_t)blockIdx.x * 256 + t] = s;
    partials[(size_t)blockIdx.x * 256 + 128 + t] = q;
  }
}

// --- reduce partials -> scale/shift, one block per channel ------------------
__global__ __launch_bounds__(256) void bn_finalize(
    const float* __restrict__ partials, int nb, int C, int M,
    const float* __restrict__ g, const float* __restrict__ bt,
    float* __restrict__ ss) {
  int c = blockIdx.x;
  int t = threadIdx.x;
  float s = 0.f, s2 = 0.f;
  for (int b = t; b < nb; b += 256) {
    s += partials[(size_t)b * 2 * C + c];
    s2 += partials[(size_t)b * 2 * C + C + c];
  }
#pragma unroll
  for (int off = 32; off >= 1; off >>= 1) {
    s += __shfl_xor(s, off);
    s2 += __shfl_xor(s2, off);
  }
  __shared__ float sh[4][2];
  int wave = t >> 6, lane = t & 63;
  if (lane == 0) { sh[wave][0] = s; sh[wave][1] = s2; }
  __syncthreads();
  if (t == 0) {
    s = sh[0][0] + sh[1][0] + sh[2][0] + sh[3][0];
    s2 = sh[0][1] + sh[1][1] + sh[2][1] + sh[3][1];
    float mean = s / (float)M;
    float var = s2 / (float)M - mean * mean;
    float sc = g[c] * rsqrtf(var + 1e-5f);
    ss[c] = sc;
    ss[C + c] = bt[c] - mean * sc;
  }
}

// --- elementwise BN + ReLU, bf16 in/out; zero-pads rows [M, Mpad) -----------
__global__ __launch_bounds__(256) void bnrelu(
    const unsigned short* __restrict__ P, const float* __restrict__ ss,
    unsigned short* __restrict__ Aout, int total, int total2, int Cmask) {
  int i = (blockIdx.x * 256 + threadIdx.x) * 8;
  if (i >= total2) return;
  u16x8 o = {0, 0, 0, 0, 0, 0, 0, 0};
  if (i < total) {
    u16x8 v = *(const u16x8*)(P + i);
    int c0 = i & Cmask;
    int C = Cmask + 1;
#pragma unroll
    for (int j = 0; j < 8; ++j) {
      float f = bfu2f(v[j]) * ss[c0 + j] + ss[C + c0 + j];
      o[j] = f2bfu(fmaxf(f, 0.f));
    }
  }
  *(u16x8*)(Aout + i) = o;
}

// --- final: out[c][n] = relu(bn3(c3p) + bnsc(scp)), transposed fp32 write ---
__global__ __launch_bounds__(256) void final_out(
    const unsigned short* __restrict__ c3p, const unsigned short* __restrict__ scp,
    const float* __restrict__ ss3, const float* __restrict__ sssc,
    float* __restrict__ out, int M) {
  __shared__ float tile[64][65];
  int n0 = blockIdx.x * 64, c0 = blockIdx.y * 64;
  int t = threadIdx.x;
  int cl = t & 63;
#pragma unroll
  for (int i = 0; i < 16; ++i) {
    int nl = i * 4 + (t >> 6);
    int n = n0 + nl;
    float v = 0.f;
    if (n < M) {
      int c = c0 + cl;
      float a = bfu2f(c3p[(size_t)n * 512 + c]) * ss3[c] + ss3[512 + c];
      float b = bfu2f(scp[(size_t)n * 512 + c]) * sssc[c] + sssc[512 + c];
      v = fmaxf(a + b, 0.f);
    }
    tile[nl][cl] = v;
  }
  __syncthreads();
  int nl = t & 63;
#pragma unroll
  for (int i = 0; i < 16; ++i) {
    int cl2 = i * 4 + (t >> 6);
    int n = n0 + nl;
    if (n < M) out[(size_t)(c0 + cl2) * M + n0 + nl] = tile[nl][cl2];
  }
}

extern "C" void kernel_launch(void* const* d_in, const int* in_sizes, int n_in,
                              void* d_out, int out_size, void* d_ws, size_t ws_size,
                              hipStream_t stream) {
  const float* x   = (const float*)d_in[0];
  const int* neigh = (const int*)d_in[1];
  const float* W1a = (const float*)d_in[2];
  const float* g1a = (const float*)d_in[3];
  const float* b1a = (const float*)d_in[4];
  const float* W3  = (const float*)d_in[5];
  const float* g3  = (const float*)d_in[6];
  const float* b3  = (const float*)d_in[7];
  const float* W1b = (const float*)d_in[8];
  const float* g1b = (const float*)d_in[9];
  const float* b1b = (const float*)d_in[10];
  const float* Wc  = (const float*)d_in[11];
  const float* gc  = (const float*)d_in[12];
  const float* bc  = (const float*)d_in[13];
  float* out = (float*)d_out;

  const int M = in_sizes[1] / 27;          // 60000 nodes (< 65536: nidx ushort)
  const int MT = (M + 63) / 64;            // 938 (transpose/final tiles)
  const int MTO = (M + 127) / 128;         // 469 (GEMM row tiles)
  // Mpad = MT*64 = MTO*128 = 60032

  char* ws = (char*)d_ws;
  unsigned short* h   = (unsigned short*)(ws + 0);           // [60032][256] bf16
  unsigned short* wA  = (unsigned short*)(ws + 30736384);    // [60032][128]
  unsigned short* wP  = (unsigned short*)(ws + 46104576);    // [M][128]
  unsigned short* c3p = (unsigned short*)(ws + 61464576);    // [M][512]
  unsigned short* scp = (unsigned short*)(ws + 122904576);   // [M][512]
  unsigned short* w1a = (unsigned short*)(ws + 184344576);   // [128][256]
  unsigned short* w3t = (unsigned short*)(ws + 184410112);   // [27][128][128] d-major
  unsigned short* w1b = (unsigned short*)(ws + 185294848);   // [512][128]
  unsigned short* wc  = (unsigned short*)(ws + 185425920);   // [512][256]
  float* ss1  = (float*)(ws + 185688064);
  float* ss2  = (float*)(ws + 185692160);
  float* ss3  = (float*)(ws + 185696256);
  float* sssc = (float*)(ws + 185700352);

  // Partials live in ws regions that are dead at their point of use:
  float* part12 = (float*)c3p;   // stage-1/2 stats (c3p not yet written)
  float* part3  = (float*)scp;   // stage-3 stats (read before gemmsc writes scp)
  float* partsc = (float*)wP;    // shortcut stats (wP dead after bnrelu2)

  prep_weights<<<1728, 256, 0, stream>>>(W1a, W3, W1b, Wc, w1a, w3t, w1b, wc);
  transpose_x<<<dim3(MT, 4), 256, 0, stream>>>(x, h, M);

  const int total = M * 128, total2 = (MT * 64) * 128;
  const int bnGrid = (total2 / 8 + 255) / 256;

  // c1 = relu(bn(h @ W1a^T))   (wA pad rows zeroed for octree gather)
  gemm128<<<dim3(1, MTO), 256, 0, stream>>>(h, w1a, wP, part12, M, 256, 128);
  bn_finalize<<<128, 256, 0, stream>>>(part12, MTO, 128, M, g1a, b1a, ss1);
  bnrelu<<<bnGrid, 256, 0, stream>>>(wP, ss1, wA, total, total2, 127);

  // c2 = relu(bn(octree_conv(c1)))
  octree_gemm<<<MTO, 512, 0, stream>>>(wA, neigh, w3t, wP, part12, M);
  bn_finalize<<<128, 256, 0, stream>>>(part12, MTO, 128, M, g3, b3, ss2);
  bnrelu<<<bnGrid, 256, 0, stream>>>(wP, ss2, wA, total, total2, 127);

  // c3_pre = c2 @ W1b^T (stats -> part3, consumed before gemmsc writes scp)
  gemm128<<<dim3(4, MTO), 256, 0, stream>>>(wA, w1b, c3p, part3, M, 128, 512);
  bn_finalize<<<512, 256, 0, stream>>>(part3, MTO, 512, M, g1b, b1b, ss3);

  // sc_pre = h @ Wc^T
  gemm128<<<dim3(4, MTO), 256, 0, stream>>>(h, wc, scp, partsc, M, 256, 512);
  bn_finalize<<<512, 256, 0, stream>>>(partsc, MTO, 512, M, gc, bc, sssc);

  // out = relu(bn(c3_pre) + bn(sc_pre)), transposed to [512][M]
  final_out<<<dim3(MT, 8), 256, 0, stream>>>(c3p, scp, ss3, sssc, out, M);
}

// Round 7
// 250.205 us; speedup vs baseline: 4.9204x; 1.0141x over previous
//
#include <hip/hip_runtime.h>

// ---------------------------------------------------------------------------
// OctreeResBlock on MI355X (gfx950), round 6:
//  - gemm128 (dense): port the r6 counted-vmcnt pipeline (raw s_barrier +
//    s_waitcnt vmcnt(8)) — r5/r6 showed __syncthreads drains vmcnt(0) and
//    serializes every phase. Octree got +18% from this; dense was left behind.
//  - final_out: 8B/lane ushort4 reads (was 2B/lane), [64][129] fp32 tile,
//    conflict-free readout, 128-channel blocks.
//  - octree_gemm unchanged from r6 (68us, near gather/MFMA floor).
// ---------------------------------------------------------------------------

typedef __bf16 bf16x8 __attribute__((ext_vector_type(8)));
typedef float f32x4 __attribute__((ext_vector_type(4)));
typedef unsigned short u16x8 __attribute__((ext_vector_type(8)));
typedef unsigned short u16x4 __attribute__((ext_vector_type(4)));

__device__ __forceinline__ unsigned short f2bfu(float f) {
  union { float f; unsigned u; } v; v.f = f;
  unsigned r = v.u + 0x7fffu + ((v.u >> 16) & 1u);   // round-to-nearest-even
  return (unsigned short)(r >> 16);
}
__device__ __forceinline__ float bfu2f(unsigned short s) {
  union { unsigned u; float f; } v; v.u = ((unsigned)s) << 16;
  return v.f;
}

// async global->LDS, 16B per lane; dest = wave-uniform base + lane*16
__device__ __forceinline__ void gload_lds16(const unsigned short* g, unsigned short* l) {
  __builtin_amdgcn_global_load_lds(
      (const __attribute__((address_space(1))) unsigned int*)(unsigned long long)g,
      (__attribute__((address_space(3))) unsigned int*)(unsigned int)(unsigned long long)l,
      16, 0, 0);
}

// --- weights prep: fp32 -> bf16; W3 [k][c][d] -> w3t [k][d][c] --------------
__global__ __launch_bounds__(256) void prep_weights(
    const float* __restrict__ W1a, const float* __restrict__ W3,
    const float* __restrict__ W1b, const float* __restrict__ Wc,
    unsigned short* __restrict__ w1a, unsigned short* __restrict__ w3t,
    unsigned short* __restrict__ w1b, unsigned short* __restrict__ wc) {
  int i = blockIdx.x * 256 + threadIdx.x;
  int stride = gridDim.x * 256;
  for (; i < 442368; i += stride) {
    if (i < 32768)  w1a[i] = f2bfu(W1a[i]);
    if (i < 65536)  w1b[i] = f2bfu(W1b[i]);
    if (i < 131072) wc[i]  = f2bfu(Wc[i]);
    int k = i >> 14, rr = i & 16383;
    int d = rr >> 7, c = rr & 127;
    w3t[i] = f2bfu(W3[(k << 14) + (c << 7) + d]);
  }
}

// --- x [256][M] fp32 -> h [Mpad][256] bf16 (zero rows beyond M) -------------
__global__ __launch_bounds__(256) void transpose_x(
    const float* __restrict__ x, unsigned short* __restrict__ h, int M) {
  __shared__ float tile[64][65];
  int n0 = blockIdx.x * 64, c0 = blockIdx.y * 64;
  int t = threadIdx.x;
  int nl = t & 63;
#pragma unroll
  for (int i = 0; i < 16; ++i) {
    int cl = i * 4 + (t >> 6);
    int n = n0 + nl;
    tile[cl][nl] = (n < M) ? x[(size_t)(c0 + cl) * M + n] : 0.f;
  }
  __syncthreads();
  int cl = t & 63;
#pragma unroll
  for (int i = 0; i < 16; ++i) {
    int nl2 = i * 4 + (t >> 6);
    int n = n0 + nl2;
    h[(size_t)n * 256 + c0 + cl] = f2bfu(tile[cl][nl2]);   // pad rows get zeros
  }
}

// --- dense GEMM: C[M][Nc] = A[Mpad][Kd] * W[Nc][Kd]^T -----------------------
// 128x128 tile, 4 waves (2x2), BK=64, counted-vmcnt 2-deep pipeline.
__global__ __launch_bounds__(256) void gemm128(
    const unsigned short* __restrict__ A, const unsigned short* __restrict__ W,
    unsigned short* __restrict__ C, float* __restrict__ partials,
    int M, int Kd, int Nc) {
  __shared__ unsigned short sA[2][128 * 64];
  __shared__ unsigned short sB[2][128 * 64];
  __shared__ float sStat[4][2][128];
  int t = threadIdx.x, wave = t >> 6, lane = t & 63;
  int n0 = blockIdx.x * 128, m0 = blockIdx.y * 128;
  int wr = wave >> 1, wcc = wave & 1;
  int l4 = lane >> 4, lc = lane & 15, lc7 = lc & 7;
  int lrow = lane >> 3, lch = lane & 7;
  f32x4 acc[4][4] = {};
  const int np = Kd >> 6;

  auto STAGE = [&](int p, int buf) {
    int k0 = p << 6;
#pragma unroll
    for (int i = 0; i < 4; ++i) {
      int row = wave * 32 + i * 8 + lrow;
      int sc = lch ^ (row & 7);
      gload_lds16(A + (size_t)(m0 + row) * Kd + k0 + sc * 8, &sA[buf][(wave * 32 + i * 8) * 64]);
    }
#pragma unroll
    for (int i = 0; i < 4; ++i) {
      int row = wave * 32 + i * 8 + lrow;
      int sc = lch ^ (row & 7);
      gload_lds16(W + (size_t)(n0 + row) * Kd + k0 + sc * 8, &sB[buf][(wave * 32 + i * 8) * 64]);
    }
  };
  auto COMPUTE = [&](int buf) {
#pragma unroll
    for (int kk = 0; kk < 2; ++kk) {
      bf16x8 af[4], bfr[4];
#pragma unroll
      for (int mi = 0; mi < 4; ++mi) {
        int row = wr * 64 + mi * 16 + lc;
        int chunk = (kk * 4 + l4) ^ lc7;
        af[mi] = __builtin_bit_cast(bf16x8, *(const u16x8*)(&sA[buf][row * 64 + chunk * 8]));
      }
#pragma unroll
      for (int ni = 0; ni < 4; ++ni) {
        int row = wcc * 64 + ni * 16 + lc;
        int chunk = (kk * 4 + l4) ^ lc7;
        bfr[ni] = __builtin_bit_cast(bf16x8, *(const u16x8*)(&sB[buf][row * 64 + chunk * 8]));
      }
      __builtin_amdgcn_s_setprio(1);
#pragma unroll
      for (int mi = 0; mi < 4; ++mi)
#pragma unroll
        for (int ni = 0; ni < 4; ++ni)
          acc[mi][ni] = __builtin_amdgcn_mfma_f32_16x16x32_bf16(af[mi], bfr[ni], acc[mi][ni], 0, 0, 0);
      __builtin_amdgcn_s_setprio(0);
    }
  };

  STAGE(0, 0);
  for (int p = 0; p < np; ++p) {
    int cur = p & 1;
    if (p < np - 1) {
      STAGE(p + 1, cur ^ 1);
      asm volatile("s_waitcnt vmcnt(8)" ::: "memory");   // own cur-stage landed
    } else {
      asm volatile("s_waitcnt vmcnt(0)" ::: "memory");
    }
    __builtin_amdgcn_sched_barrier(0);
    __builtin_amdgcn_s_barrier();                         // raw: no vmcnt drain
    __builtin_amdgcn_sched_barrier(0);
    COMPUTE(cur);
    __builtin_amdgcn_sched_barrier(0);                    // reads pinned above
    __builtin_amdgcn_s_barrier();                         // cur readable until here
  }

#pragma unroll
  for (int ni = 0; ni < 4; ++ni) {
    float s = 0.f, q = 0.f;
    int col = wcc * 64 + ni * 16 + lc;
#pragma unroll
    for (int mi = 0; mi < 4; ++mi)
#pragma unroll
      for (int j = 0; j < 4; ++j) {
        int n = m0 + wr * 64 + mi * 16 + l4 * 4 + j;
        unsigned short u = f2bfu(acc[mi][ni][j]);
        if (n < M) C[(size_t)n * Nc + n0 + col] = u;
        float v = bfu2f(u);
        s += v; q += v * v;
      }
    s += __shfl_xor(s, 16); s += __shfl_xor(s, 32);
    q += __shfl_xor(q, 16); q += __shfl_xor(q, 32);
    if (lane < 16) {
      sStat[wave][0][col] = s;
      sStat[wave][1][col] = q;
    }
  }
  __syncthreads();
  if (t < 128) {
    int wcs = t >> 6;
    float s = sStat[wcs][0][t] + sStat[wcs + 2][0][t];
    float q = sStat[wcs][1][t] + sStat[wcs + 2][1][t];
    partials[(size_t)blockIdx.y * (2 * Nc) + n0 + t] = s;
    partials[(size_t)blockIdx.y * (2 * Nc) + Nc + n0 + t] = q;
  }
}

// --- octree conv (unchanged r6): counted-vmcnt gather pipeline --------------
__global__ __launch_bounds__(512, 4) void octree_gemm(
    const unsigned short* __restrict__ c1, const int* __restrict__ neigh,
    const unsigned short* __restrict__ w3t, unsigned short* __restrict__ c2p,
    float* __restrict__ partials, int M) {
  __shared__ unsigned short sA[2][128 * 64];
  __shared__ unsigned short sB[2][128 * 64];
  __shared__ union {
    unsigned short nidx[128 * 27];
    float stat[8][2][128];
  } u;
  int t = threadIdx.x, wave = t >> 6, lane = t & 63;
  int m0 = blockIdx.x * 128;
  for (int i = t; i < 128 * 27; i += 512) {
    int row = i / 27;
    u.nidx[i] = (unsigned short)((m0 + row < M) ? neigh[(size_t)m0 * 27 + i] : M);
  }
  __syncthreads();

  int wr = wave >> 1, wcc = wave & 1;
  int l4 = lane >> 4, lc = lane & 15, lc7 = lc & 7;
  int lrow = lane >> 3, lch = lane & 7;
  f32x4 acc[2][4] = {};

  auto STAGE = [&](int p, int buf) {
    int k = p >> 1, c0 = (p & 1) << 6;
#pragma unroll
    for (int i = 0; i < 2; ++i) {
      int row = wave * 16 + i * 8 + lrow;
      int nr = u.nidx[row * 27 + k];
      int sc = lch ^ (row & 7);
      gload_lds16(c1 + ((size_t)nr << 7) + c0 + sc * 8, &sA[buf][(wave * 16 + i * 8) * 64]);
    }
    const unsigned short* wk = w3t + ((size_t)k << 14);
#pragma unroll
    for (int i = 0; i < 2; ++i) {
      int row = wave * 16 + i * 8 + lrow;
      int sc = lch ^ (row & 7);
      gload_lds16(wk + ((size_t)row << 7) + c0 + sc * 8, &sB[buf][(wave * 16 + i * 8) * 64]);
    }
  };
  auto COMPUTE = [&](int buf) {
#pragma unroll
    for (int kk = 0; kk < 2; ++kk) {
      bf16x8 af[2], bfr[4];
#pragma unroll
      for (int mi = 0; mi < 2; ++mi) {
        int row = wr * 32 + mi * 16 + lc;
        int chunk = (kk * 4 + l4) ^ lc7;
        af[mi] = __builtin_bit_cast(bf16x8, *(const u16x8*)(&sA[buf][row * 64 + chunk * 8]));
      }
#pragma unroll
      for (int ni = 0; ni < 4; ++ni) {
        int row = wcc * 64 + ni * 16 + lc;
        int chunk = (kk * 4 + l4) ^ lc7;
        bfr[ni] = __builtin_bit_cast(bf16x8, *(const u16x8*)(&sB[buf][row * 64 + chunk * 8]));
      }
      __builtin_amdgcn_s_setprio(1);
#pragma unroll
      for (int mi = 0; mi < 2; ++mi)
#pragma unroll
        for (int ni = 0; ni < 4; ++ni)
          acc[mi][ni] = __builtin_amdgcn_mfma_f32_16x16x32_bf16(af[mi], bfr[ni], acc[mi][ni], 0, 0, 0);
      __builtin_amdgcn_s_setprio(0);
    }
  };

  STAGE(0, 0);
  for (int p = 0; p < 54; ++p) {
    int cur = p & 1;
    if (p < 53) {
      STAGE(p + 1, cur ^ 1);
      asm volatile("s_waitcnt vmcnt(4)" ::: "memory");
    } else {
      asm volatile("s_waitcnt vmcnt(0)" ::: "memory");
    }
    __builtin_amdgcn_sched_barrier(0);
    __builtin_amdgcn_s_barrier();
    __builtin_amdgcn_sched_barrier(0);
    COMPUTE(cur);
    __builtin_amdgcn_sched_barrier(0);
    __builtin_amdgcn_s_barrier();
  }

#pragma unroll
  for (int ni = 0; ni < 4; ++ni) {
    float s = 0.f, q = 0.f;
    int col = wcc * 64 + ni * 16 + lc;
#pragma unroll
    for (int mi = 0; mi < 2; ++mi)
#pragma unroll
      for (int j = 0; j < 4; ++j) {
        int n = m0 + wr * 32 + mi * 16 + l4 * 4 + j;
        unsigned short uo = f2bfu(acc[mi][ni][j]);
        if (n < M) c2p[(size_t)n * 128 + col] = uo;
        float v = bfu2f(uo);
        s += v; q += v * v;
      }
    s += __shfl_xor(s, 16); s += __shfl_xor(s, 32);
    q += __shfl_xor(q, 16); q += __shfl_xor(q, 32);
    if (lane < 16) {
      u.stat[wave][0][col] = s;
      u.stat[wave][1][col] = q;
    }
  }
  __syncthreads();
  if (t < 128) {
    int wcs = t >> 6;
    float s = 0.f, q = 0.f;
#pragma unroll
    for (int g = 0; g < 4; ++g) {
      s += u.stat[g * 2 + wcs][0][t];
      q += u.stat[g * 2 + wcs][1][t];
    }
    partials[(size_t)blockIdx.x * 256 + t] = s;
    partials[(size_t)blockIdx.x * 256 + 128 + t] = q;
  }
}

// --- reduce partials -> scale/shift, one block per channel ------------------
__global__ __launch_bounds__(256) void bn_finalize(
    const float* __restrict__ partials, int nb, int C, int M,
    const float* __restrict__ g, const float* __restrict__ bt,
    float* __restrict__ ss) {
  int c = blockIdx.x;
  int t = threadIdx.x;
  float s = 0.f, s2 = 0.f;
  for (int b = t; b < nb; b += 256) {
    s += partials[(size_t)b * 2 * C + c];
    s2 += partials[(size_t)b * 2 * C + C + c];
  }
#pragma unroll
  for (int off = 32; off >= 1; off >>= 1) {
    s += __shfl_xor(s, off);
    s2 += __shfl_xor(s2, off);
  }
  __shared__ float sh[4][2];
  int wave = t >> 6, lane = t & 63;
  if (lane == 0) { sh[wave][0] = s; sh[wave][1] = s2; }
  __syncthreads();
  if (t == 0) {
    s = sh[0][0] + sh[1][0] + sh[2][0] + sh[3][0];
    s2 = sh[0][1] + sh[1][1] + sh[2][1] + sh[3][1];
    float mean = s / (float)M;
    float var = s2 / (float)M - mean * mean;
    float sc = g[c] * rsqrtf(var + 1e-5f);
    ss[c] = sc;
    ss[C + c] = bt[c] - mean * sc;
  }
}

// --- elementwise BN + ReLU, bf16 in/out; zero-pads rows [M, Mpad) -----------
__global__ __launch_bounds__(256) void bnrelu(
    const unsigned short* __restrict__ P, const float* __restrict__ ss,
    unsigned short* __restrict__ Aout, int total, int total2, int Cmask) {
  int i = (blockIdx.x * 256 + threadIdx.x) * 8;
  if (i >= total2) return;
  u16x8 o = {0, 0, 0, 0, 0, 0, 0, 0};
  if (i < total) {
    u16x8 v = *(const u16x8*)(P + i);
    int c0 = i & Cmask;
    int C = Cmask + 1;
#pragma unroll
    for (int j = 0; j < 8; ++j) {
      float f = bfu2f(v[j]) * ss[c0 + j] + ss[C + c0 + j];
      o[j] = f2bfu(fmaxf(f, 0.f));
    }
  }
  *(u16x8*)(Aout + i) = o;
}

// --- final: out[c][n] = relu(bn3(c3p) + bnsc(scp)), transposed fp32 write ---
// 64n x 128c per block; 8B/lane reads, [64][129] fp32 tile, coalesced stores.
__global__ __launch_bounds__(256) void final_out(
    const unsigned short* __restrict__ c3p, const unsigned short* __restrict__ scp,
    const float* __restrict__ ss3, const float* __restrict__ sssc,
    float* __restrict__ out, int M) {
  __shared__ float tile[64][129];
  int n0 = blockIdx.x * 64, c0 = blockIdx.y * 128;
  int t = threadIdx.x;
  int rowg = t >> 5, cg = (t & 31) * 4;
#pragma unroll
  for (int ps = 0; ps < 8; ++ps) {
    int nl = ps * 8 + rowg;
    int n = n0 + nl;
    float v0 = 0.f, v1 = 0.f, v2 = 0.f, v3 = 0.f;
    if (n < M) {
      u16x4 a = *(const u16x4*)(c3p + (size_t)n * 512 + c0 + cg);
      u16x4 b = *(const u16x4*)(scp + (size_t)n * 512 + c0 + cg);
      int c = c0 + cg;
      v0 = fmaxf(bfu2f(a[0]) * ss3[c + 0] + ss3[512 + c + 0] + bfu2f(b[0]) * sssc[c + 0] + sssc[512 + c + 0], 0.f);
      v1 = fmaxf(bfu2f(a[1]) * ss3[c + 1] + ss3[512 + c + 1] + bfu2f(b[1]) * sssc[c + 1] + sssc[512 + c + 1], 0.f);
      v2 = fmaxf(bfu2f(a[2]) * ss3[c + 2] + ss3[512 + c + 2] + bfu2f(b[2]) * sssc[c + 2] + sssc[512 + c + 2], 0.f);
      v3 = fmaxf(bfu2f(a[3]) * ss3[c + 3] + ss3[512 + c + 3] + bfu2f(b[3]) * sssc[c + 3] + sssc[512 + c + 3], 0.f);
    }
    tile[nl][cg + 0] = v0;
    tile[nl][cg + 1] = v1;
    tile[nl][cg + 2] = v2;
    tile[nl][cg + 3] = v3;
  }
  __syncthreads();
  int nl = t & 63, cq = t >> 6;
  int n = n0 + nl;
  if (n < M) {
#pragma unroll
    for (int i = 0; i < 32; ++i) {
      int cl = i * 4 + cq;
      out[(size_t)(c0 + cl) * M + n] = tile[nl][cl];
    }
  }
}

extern "C" void kernel_launch(void* const* d_in, const int* in_sizes, int n_in,
                              void* d_out, int out_size, void* d_ws, size_t ws_size,
                              hipStream_t stream) {
  const float* x   = (const float*)d_in[0];
  const int* neigh = (const int*)d_in[1];
  const float* W1a = (const float*)d_in[2];
  const float* g1a = (const float*)d_in[3];
  const float* b1a = (const float*)d_in[4];
  const float* W3  = (const float*)d_in[5];
  const float* g3  = (const float*)d_in[6];
  const float* b3  = (const float*)d_in[7];
  const float* W1b = (const float*)d_in[8];
  const float* g1b = (const float*)d_in[9];
  const float* b1b = (const float*)d_in[10];
  const float* Wc  = (const float*)d_in[11];
  const float* gc  = (const float*)d_in[12];
  const float* bc  = (const float*)d_in[13];
  float* out = (float*)d_out;

  const int M = in_sizes[1] / 27;          // 60000 nodes (< 65536: nidx ushort)
  const int MT = (M + 63) / 64;            // 938 (transpose/final tiles)
  const int MTO = (M + 127) / 128;         // 469 (GEMM row tiles)
  // Mpad = MT*64 = MTO*128 = 60032

  char* ws = (char*)d_ws;
  unsigned short* h   = (unsigned short*)(ws + 0);           // [60032][256] bf16
  unsigned short* wA  = (unsigned short*)(ws + 30736384);    // [60032][128]
  unsigned short* wP  = (unsigned short*)(ws + 46104576);    // [M][128]
  unsigned short* c3p = (unsigned short*)(ws + 61464576);    // [M][512]
  unsigned short* scp = (unsigned short*)(ws + 122904576);   // [M][512]
  unsigned short* w1a = (unsigned short*)(ws + 184344576);   // [128][256]
  unsigned short* w3t = (unsigned short*)(ws + 184410112);   // [27][128][128] d-major
  unsigned short* w1b = (unsigned short*)(ws + 185294848);   // [512][128]
  unsigned short* wc  = (unsigned short*)(ws + 185425920);   // [512][256]
  float* ss1  = (float*)(ws + 185688064);
  float* ss2  = (float*)(ws + 185692160);
  float* ss3  = (float*)(ws + 185696256);
  float* sssc = (float*)(ws + 185700352);

  // Partials live in ws regions that are dead at their point of use:
  float* part12 = (float*)c3p;   // stage-1/2 stats (c3p not yet written)
  float* part3  = (float*)scp;   // stage-3 stats (read before gemmsc writes scp)
  float* partsc = (float*)wP;    // shortcut stats (wP dead after bnrelu2)

  prep_weights<<<1728, 256, 0, stream>>>(W1a, W3, W1b, Wc, w1a, w3t, w1b, wc);
  transpose_x<<<dim3(MT, 4), 256, 0, stream>>>(x, h, M);

  const int total = M * 128, total2 = (MT * 64) * 128;
  const int bnGrid = (total2 / 8 + 255) / 256;

  // c1 = relu(bn(h @ W1a^T))   (wA pad rows zeroed for octree gather)
  gemm128<<<dim3(1, MTO), 256, 0, stream>>>(h, w1a, wP, part12, M, 256, 128);
  bn_finalize<<<128, 256, 0, stream>>>(part12, MTO, 128, M, g1a, b1a, ss1);
  bnrelu<<<bnGrid, 256, 0, stream>>>(wP, ss1, wA, total, total2, 127);

  // c2 = relu(bn(octree_conv(c1)))
  octree_gemm<<<MTO, 512, 0, stream>>>(wA, neigh, w3t, wP, part12, M);
  bn_finalize<<<128, 256, 0, stream>>>(part12, MTO, 128, M, g3, b3, ss2);
  bnrelu<<<bnGrid, 256, 0, stream>>>(wP, ss2, wA, total, total2, 127);

  // c3_pre = c2 @ W1b^T (stats -> part3, consumed before gemmsc writes scp)
  gemm128<<<dim3(4, MTO), 256, 0, stream>>>(wA, w1b, c3p, part3, M, 128, 512);
  bn_finalize<<<512, 256, 0, stream>>>(part3, MTO, 512, M, g1b, b1b, ss3);

  // sc_pre = h @ Wc^T
  gemm128<<<dim3(4, MTO), 256, 0, stream>>>(h, wc, scp, partsc, M, 256, 512);
  bn_finalize<<<512, 256, 0, stream>>>(partsc, MTO, 512, M, gc, bc, sssc);

  // out = relu(bn(c3_pre) + bn(sc_pre)), transposed to [512][M]
  final_out<<<dim3(MT, 4), 256, 0, stream>>>(c3p, scp, ss3, sssc, out, M);
}

// Round 8
// 237.142 us; speedup vs baseline: 5.1915x; 1.0551x over previous
//
#include <hip/hip_runtime.h>

// ---------------------------------------------------------------------------
// OctreeResBlock on MI355X (gfx950), round 7:
//  - r7 lesson: counted-vmcnt on 2-phase dense GEMM = null (regime gate);
//    octree's r6 win was 16 waves/CU. So: gemm128 -> 512 threads (16 waves/CU).
//  - Bijective chunked XCD swizzle (m204) on octree + dense grids: octree
//    gather windows are spatially local across adjacent tiles -> keep adjacent
//    tiles on the same XCD L2 (FETCH 167MB >> c1's 15.4MB says re-fetch);
//    dense: 4 col-tiles of an A-panel co-resident on one XCD.
// ---------------------------------------------------------------------------

typedef __bf16 bf16x8 __attribute__((ext_vector_type(8)));
typedef float f32x4 __attribute__((ext_vector_type(4)));
typedef unsigned short u16x8 __attribute__((ext_vector_type(8)));
typedef unsigned short u16x4 __attribute__((ext_vector_type(4)));

__device__ __forceinline__ unsigned short f2bfu(float f) {
  union { float f; unsigned u; } v; v.f = f;
  unsigned r = v.u + 0x7fffu + ((v.u >> 16) & 1u);   // round-to-nearest-even
  return (unsigned short)(r >> 16);
}
__device__ __forceinline__ float bfu2f(unsigned short s) {
  union { unsigned u; float f; } v; v.u = ((unsigned)s) << 16;
  return v.f;
}

// async global->LDS, 16B per lane; dest = wave-uniform base + lane*16
__device__ __forceinline__ void gload_lds16(const unsigned short* g, unsigned short* l) {
  __builtin_amdgcn_global_load_lds(
      (const __attribute__((address_space(1))) unsigned int*)(unsigned long long)g,
      (__attribute__((address_space(3))) unsigned int*)(unsigned int)(unsigned long long)l,
      16, 0, 0);
}

// bijective chunked XCD swizzle (m204): round-robin dispatch -> contiguous
// chunk of work per XCD.
__device__ __forceinline__ int xcd_swz(int bid, int nwg) {
  int q = nwg >> 3, r = nwg & 7;
  int xcd = bid & 7, idx = bid >> 3;
  int base = xcd < r ? xcd * (q + 1) : r * (q + 1) + (xcd - r) * q;
  return base + idx;
}

// --- weights prep: fp32 -> bf16; W3 [k][c][d] -> w3t [k][d][c] --------------
__global__ __launch_bounds__(256) void prep_weights(
    const float* __restrict__ W1a, const float* __restrict__ W3,
    const float* __restrict__ W1b, const float* __restrict__ Wc,
    unsigned short* __restrict__ w1a, unsigned short* __restrict__ w3t,
    unsigned short* __restrict__ w1b, unsigned short* __restrict__ wc) {
  int i = blockIdx.x * 256 + threadIdx.x;
  int stride = gridDim.x * 256;
  for (; i < 442368; i += stride) {
    if (i < 32768)  w1a[i] = f2bfu(W1a[i]);
    if (i < 65536)  w1b[i] = f2bfu(W1b[i]);
    if (i < 131072) wc[i]  = f2bfu(Wc[i]);
    int k = i >> 14, rr = i & 16383;
    int d = rr >> 7, c = rr & 127;
    w3t[i] = f2bfu(W3[(k << 14) + (c << 7) + d]);
  }
}

// --- x [256][M] fp32 -> h [Mpad][256] bf16 (zero rows beyond M) -------------
__global__ __launch_bounds__(256) void transpose_x(
    const float* __restrict__ x, unsigned short* __restrict__ h, int M) {
  __shared__ float tile[64][65];
  int n0 = blockIdx.x * 64, c0 = blockIdx.y * 64;
  int t = threadIdx.x;
  int nl = t & 63;
#pragma unroll
  for (int i = 0; i < 16; ++i) {
    int cl = i * 4 + (t >> 6);
    int n = n0 + nl;
    tile[cl][nl] = (n < M) ? x[(size_t)(c0 + cl) * M + n] : 0.f;
  }
  __syncthreads();
  int cl = t & 63;
#pragma unroll
  for (int i = 0; i < 16; ++i) {
    int nl2 = i * 4 + (t >> 6);
    int n = n0 + nl2;
    h[(size_t)n * 256 + c0 + cl] = f2bfu(tile[cl][nl2]);   // pad rows get zeros
  }
}

// --- dense GEMM: C[M][Nc] = A[Mpad][Kd] * W[Nc][Kd]^T -----------------------
// 128x128 tile, 512 threads (8 waves, 4x2), BK=64, counted-vmcnt pipeline,
// XCD-chunked 1-D grid (flat = rowtile*ncol + coltile).
__global__ __launch_bounds__(512, 4) void gemm128(
    const unsigned short* __restrict__ A, const unsigned short* __restrict__ W,
    unsigned short* __restrict__ C, float* __restrict__ partials,
    int M, int Kd, int Nc, int ncol) {
  __shared__ unsigned short sA[2][128 * 64];   // 32 KB
  __shared__ unsigned short sB[2][128 * 64];   // 32 KB
  __shared__ float sStat[8][2][128];           // 8 KB -> 72 KB, 2 blk/CU
  int t = threadIdx.x, wave = t >> 6, lane = t & 63;
  int flat = xcd_swz(blockIdx.x, gridDim.x);
  int n0 = (flat % ncol) * 128;
  int rowt = flat / ncol;
  int m0 = rowt * 128;
  int wr = wave >> 1, wcc = wave & 1;
  int l4 = lane >> 4, lc = lane & 15, lc7 = lc & 7;
  int lrow = lane >> 3, lch = lane & 7;
  f32x4 acc[2][4] = {};
  const int np = Kd >> 6;

  auto STAGE = [&](int p, int buf) {
    int k0 = p << 6;
#pragma unroll
    for (int i = 0; i < 2; ++i) {
      int row = wave * 16 + i * 8 + lrow;
      int sc = lch ^ (row & 7);
      gload_lds16(A + (size_t)(m0 + row) * Kd + k0 + sc * 8, &sA[buf][(wave * 16 + i * 8) * 64]);
    }
#pragma unroll
    for (int i = 0; i < 2; ++i) {
      int row = wave * 16 + i * 8 + lrow;
      int sc = lch ^ (row & 7);
      gload_lds16(W + (size_t)(n0 + row) * Kd + k0 + sc * 8, &sB[buf][(wave * 16 + i * 8) * 64]);
    }
  };
  auto COMPUTE = [&](int buf) {
#pragma unroll
    for (int kk = 0; kk < 2; ++kk) {
      bf16x8 af[2], bfr[4];
#pragma unroll
      for (int mi = 0; mi < 2; ++mi) {
        int row = wr * 32 + mi * 16 + lc;
        int chunk = (kk * 4 + l4) ^ lc7;
        af[mi] = __builtin_bit_cast(bf16x8, *(const u16x8*)(&sA[buf][row * 64 + chunk * 8]));
      }
#pragma unroll
      for (int ni = 0; ni < 4; ++ni) {
        int row = wcc * 64 + ni * 16 + lc;
        int chunk = (kk * 4 + l4) ^ lc7;
        bfr[ni] = __builtin_bit_cast(bf16x8, *(const u16x8*)(&sB[buf][row * 64 + chunk * 8]));
      }
      __builtin_amdgcn_s_setprio(1);
#pragma unroll
      for (int mi = 0; mi < 2; ++mi)
#pragma unroll
        for (int ni = 0; ni < 4; ++ni)
          acc[mi][ni] = __builtin_amdgcn_mfma_f32_16x16x32_bf16(af[mi], bfr[ni], acc[mi][ni], 0, 0, 0);
      __builtin_amdgcn_s_setprio(0);
    }
  };

  STAGE(0, 0);
  for (int p = 0; p < np; ++p) {
    int cur = p & 1;
    if (p < np - 1) {
      STAGE(p + 1, cur ^ 1);
      asm volatile("s_waitcnt vmcnt(4)" ::: "memory");   // own cur-stage landed
    } else {
      asm volatile("s_waitcnt vmcnt(0)" ::: "memory");
    }
    __builtin_amdgcn_sched_barrier(0);
    __builtin_amdgcn_s_barrier();                         // raw: no vmcnt drain
    __builtin_amdgcn_sched_barrier(0);
    COMPUTE(cur);
    __builtin_amdgcn_sched_barrier(0);                    // reads pinned above
    __builtin_amdgcn_s_barrier();                         // cur readable until here
  }

#pragma unroll
  for (int ni = 0; ni < 4; ++ni) {
    float s = 0.f, q = 0.f;
    int col = wcc * 64 + ni * 16 + lc;
#pragma unroll
    for (int mi = 0; mi < 2; ++mi)
#pragma unroll
      for (int j = 0; j < 4; ++j) {
        int n = m0 + wr * 32 + mi * 16 + l4 * 4 + j;
        unsigned short u = f2bfu(acc[mi][ni][j]);
        if (n < M) C[(size_t)n * Nc + n0 + col] = u;
        float v = bfu2f(u);   // pad rows have zero A -> contribute 0
        s += v; q += v * v;
      }
    s += __shfl_xor(s, 16); s += __shfl_xor(s, 32);
    q += __shfl_xor(q, 16); q += __shfl_xor(q, 32);
    if (lane < 16) {
      sStat[wave][0][col] = s;
      sStat[wave][1][col] = q;
    }
  }
  __syncthreads();
  if (t < 128) {
    int wcs = t >> 6;
    float s = 0.f, q = 0.f;
#pragma unroll
    for (int g = 0; g < 4; ++g) {
      s += sStat[g * 2 + wcs][0][t];
      q += sStat[g * 2 + wcs][1][t];
    }
    partials[(size_t)rowt * (2 * Nc) + n0 + t] = s;
    partials[(size_t)rowt * (2 * Nc) + Nc + n0 + t] = q;
  }
}

// --- octree conv: c2p[n][d] = sum_k sum_c c1[neigh[n][k]][c] * w3t[k][d][c] -
// r6 structure + XCD-chunked tile assignment (gather-window L2 locality).
__global__ __launch_bounds__(512, 4) void octree_gemm(
    const unsigned short* __restrict__ c1, const int* __restrict__ neigh,
    const unsigned short* __restrict__ w3t, unsigned short* __restrict__ c2p,
    float* __restrict__ partials, int M) {
  __shared__ unsigned short sA[2][128 * 64];
  __shared__ unsigned short sB[2][128 * 64];
  __shared__ union {
    unsigned short nidx[128 * 27];
    float stat[8][2][128];
  } u;
  int t = threadIdx.x, wave = t >> 6, lane = t & 63;
  int rowt = xcd_swz(blockIdx.x, gridDim.x);
  int m0 = rowt * 128;
  for (int i = t; i < 128 * 27; i += 512) {
    int row = i / 27;
    u.nidx[i] = (unsigned short)((m0 + row < M) ? neigh[(size_t)m0 * 27 + i] : M);
  }
  __syncthreads();

  int wr = wave >> 1, wcc = wave & 1;
  int l4 = lane >> 4, lc = lane & 15, lc7 = lc & 7;
  int lrow = lane >> 3, lch = lane & 7;
  f32x4 acc[2][4] = {};

  auto STAGE = [&](int p, int buf) {
    int k = p >> 1, c0 = (p & 1) << 6;
#pragma unroll
    for (int i = 0; i < 2; ++i) {
      int row = wave * 16 + i * 8 + lrow;
      int nr = u.nidx[row * 27 + k];
      int sc = lch ^ (row & 7);
      gload_lds16(c1 + ((size_t)nr << 7) + c0 + sc * 8, &sA[buf][(wave * 16 + i * 8) * 64]);
    }
    const unsigned short* wk = w3t + ((size_t)k << 14);
#pragma unroll
    for (int i = 0; i < 2; ++i) {
      int row = wave * 16 + i * 8 + lrow;
      int sc = lch ^ (row & 7);
      gload_lds16(wk + ((size_t)row << 7) + c0 + sc * 8, &sB[buf][(wave * 16 + i * 8) * 64]);
    }
  };
  auto COMPUTE = [&](int buf) {
#pragma unroll
    for (int kk = 0; kk < 2; ++kk) {
      bf16x8 af[2], bfr[4];
#pragma unroll
      for (int mi = 0; mi < 2; ++mi) {
        int row = wr * 32 + mi * 16 + lc;
        int chunk = (kk * 4 + l4) ^ lc7;
        af[mi] = __builtin_bit_cast(bf16x8, *(const u16x8*)(&sA[buf][row * 64 + chunk * 8]));
      }
#pragma unroll
      for (int ni = 0; ni < 4; ++ni) {
        int row = wcc * 64 + ni * 16 + lc;
        int chunk = (kk * 4 + l4) ^ lc7;
        bfr[ni] = __builtin_bit_cast(bf16x8, *(const u16x8*)(&sB[buf][row * 64 + chunk * 8]));
      }
      __builtin_amdgcn_s_setprio(1);
#pragma unroll
      for (int mi = 0; mi < 2; ++mi)
#pragma unroll
        for (int ni = 0; ni < 4; ++ni)
          acc[mi][ni] = __builtin_amdgcn_mfma_f32_16x16x32_bf16(af[mi], bfr[ni], acc[mi][ni], 0, 0, 0);
      __builtin_amdgcn_s_setprio(0);
    }
  };

  STAGE(0, 0);
  for (int p = 0; p < 54; ++p) {
    int cur = p & 1;
    if (p < 53) {
      STAGE(p + 1, cur ^ 1);
      asm volatile("s_waitcnt vmcnt(4)" ::: "memory");
    } else {
      asm volatile("s_waitcnt vmcnt(0)" ::: "memory");
    }
    __builtin_amdgcn_sched_barrier(0);
    __builtin_amdgcn_s_barrier();
    __builtin_amdgcn_sched_barrier(0);
    COMPUTE(cur);
    __builtin_amdgcn_sched_barrier(0);
    __builtin_amdgcn_s_barrier();
  }

#pragma unroll
  for (int ni = 0; ni < 4; ++ni) {
    float s = 0.f, q = 0.f;
    int col = wcc * 64 + ni * 16 + lc;
#pragma unroll
    for (int mi = 0; mi < 2; ++mi)
#pragma unroll
      for (int j = 0; j < 4; ++j) {
        int n = m0 + wr * 32 + mi * 16 + l4 * 4 + j;
        unsigned short uo = f2bfu(acc[mi][ni][j]);
        if (n < M) c2p[(size_t)n * 128 + col] = uo;
        float v = bfu2f(uo);
        s += v; q += v * v;
      }
    s += __shfl_xor(s, 16); s += __shfl_xor(s, 32);
    q += __shfl_xor(q, 16); q += __shfl_xor(q, 32);
    if (lane < 16) {
      u.stat[wave][0][col] = s;
      u.stat[wave][1][col] = q;
    }
  }
  __syncthreads();
  if (t < 128) {
    int wcs = t >> 6;
    float s = 0.f, q = 0.f;
#pragma unroll
    for (int g = 0; g < 4; ++g) {
      s += u.stat[g * 2 + wcs][0][t];
      q += u.stat[g * 2 + wcs][1][t];
    }
    partials[(size_t)rowt * 256 + t] = s;
    partials[(size_t)rowt * 256 + 128 + t] = q;
  }
}

// --- reduce partials -> scale/shift, one block per channel ------------------
__global__ __launch_bounds__(256) void bn_finalize(
    const float* __restrict__ partials, int nb, int C, int M,
    const float* __restrict__ g, const float* __restrict__ bt,
    float* __restrict__ ss) {
  int c = blockIdx.x;
  int t = threadIdx.x;
  float s = 0.f, s2 = 0.f;
  for (int b = t; b < nb; b += 256) {
    s += partials[(size_t)b * 2 * C + c];
    s2 += partials[(size_t)b * 2 * C + C + c];
  }
#pragma unroll
  for (int off = 32; off >= 1; off >>= 1) {
    s += __shfl_xor(s, off);
    s2 += __shfl_xor(s2, off);
  }
  __shared__ float sh[4][2];
  int wave = t >> 6, lane = t & 63;
  if (lane == 0) { sh[wave][0] = s; sh[wave][1] = s2; }
  __syncthreads();
  if (t == 0) {
    s = sh[0][0] + sh[1][0] + sh[2][0] + sh[3][0];
    s2 = sh[0][1] + sh[1][1] + sh[2][1] + sh[3][1];
    float mean = s / (float)M;
    float var = s2 / (float)M - mean * mean;
    float sc = g[c] * rsqrtf(var + 1e-5f);
    ss[c] = sc;
    ss[C + c] = bt[c] - mean * sc;
  }
}

// --- elementwise BN + ReLU, bf16 in/out; zero-pads rows [M, Mpad) -----------
__global__ __launch_bounds__(256) void bnrelu(
    const unsigned short* __restrict__ P, const float* __restrict__ ss,
    unsigned short* __restrict__ Aout, int total, int total2, int Cmask) {
  int i = (blockIdx.x * 256 + threadIdx.x) * 8;
  if (i >= total2) return;
  u16x8 o = {0, 0, 0, 0, 0, 0, 0, 0};
  if (i < total) {
    u16x8 v = *(const u16x8*)(P + i);
    int c0 = i & Cmask;
    int C = Cmask + 1;
#pragma unroll
    for (int j = 0; j < 8; ++j) {
      float f = bfu2f(v[j]) * ss[c0 + j] + ss[C + c0 + j];
      o[j] = f2bfu(fmaxf(f, 0.f));
    }
  }
  *(u16x8*)(Aout + i) = o;
}

// --- final: out[c][n] = relu(bn3(c3p) + bnsc(scp)), transposed fp32 write ---
__global__ __launch_bounds__(256) void final_out(
    const unsigned short* __restrict__ c3p, const unsigned short* __restrict__ scp,
    const float* __restrict__ ss3, const float* __restrict__ sssc,
    float* __restrict__ out, int M) {
  __shared__ float tile[64][129];
  int n0 = blockIdx.x * 64, c0 = blockIdx.y * 128;
  int t = threadIdx.x;
  int rowg = t >> 5, cg = (t & 31) * 4;
#pragma unroll
  for (int ps = 0; ps < 8; ++ps) {
    int nl = ps * 8 + rowg;
    int n = n0 + nl;
    float v0 = 0.f, v1 = 0.f, v2 = 0.f, v3 = 0.f;
    if (n < M) {
      u16x4 a = *(const u16x4*)(c3p + (size_t)n * 512 + c0 + cg);
      u16x4 b = *(const u16x4*)(scp + (size_t)n * 512 + c0 + cg);
      int c = c0 + cg;
      v0 = fmaxf(bfu2f(a[0]) * ss3[c + 0] + ss3[512 + c + 0] + bfu2f(b[0]) * sssc[c + 0] + sssc[512 + c + 0], 0.f);
      v1 = fmaxf(bfu2f(a[1]) * ss3[c + 1] + ss3[512 + c + 1] + bfu2f(b[1]) * sssc[c + 1] + sssc[512 + c + 1], 0.f);
      v2 = fmaxf(bfu2f(a[2]) * ss3[c + 2] + ss3[512 + c + 2] + bfu2f(b[2]) * sssc[c + 2] + sssc[512 + c + 2], 0.f);
      v3 = fmaxf(bfu2f(a[3]) * ss3[c + 3] + ss3[512 + c + 3] + bfu2f(b[3]) * sssc[c + 3] + sssc[512 + c + 3], 0.f);
    }
    tile[nl][cg + 0] = v0;
    tile[nl][cg + 1] = v1;
    tile[nl][cg + 2] = v2;
    tile[nl][cg + 3] = v3;
  }
  __syncthreads();
  int nl = t & 63, cq = t >> 6;
  int n = n0 + nl;
  if (n < M) {
#pragma unroll
    for (int i = 0; i < 32; ++i) {
      int cl = i * 4 + cq;
      out[(size_t)(c0 + cl) * M + n] = tile[nl][cl];
    }
  }
}

extern "C" void kernel_launch(void* const* d_in, const int* in_sizes, int n_in,
                              void* d_out, int out_size, void* d_ws, size_t ws_size,
                              hipStream_t stream) {
  const float* x   = (const float*)d_in[0];
  const int* neigh = (const int*)d_in[1];
  const float* W1a = (const float*)d_in[2];
  const float* g1a = (const float*)d_in[3];
  const float* b1a = (const float*)d_in[4];
  const float* W3  = (const float*)d_in[5];
  const float* g3  = (const float*)d_in[6];
  const float* b3  = (const float*)d_in[7];
  const float* W1b = (const float*)d_in[8];
  const float* g1b = (const float*)d_in[9];
  const float* b1b = (const float*)d_in[10];
  const float* Wc  = (const float*)d_in[11];
  const float* gc  = (const float*)d_in[12];
  const float* bc  = (const float*)d_in[13];
  float* out = (float*)d_out;

  const int M = in_sizes[1] / 27;          // 60000 nodes (< 65536: nidx ushort)
  const int MT = (M + 63) / 64;            // 938 (transpose/final tiles)
  const int MTO = (M + 127) / 128;         // 469 (GEMM row tiles)
  // Mpad = MT*64 = MTO*128 = 60032

  char* ws = (char*)d_ws;
  unsigned short* h   = (unsigned short*)(ws + 0);           // [60032][256] bf16
  unsigned short* wA  = (unsigned short*)(ws + 30736384);    // [60032][128]
  unsigned short* wP  = (unsigned short*)(ws + 46104576);    // [M][128]
  unsigned short* c3p = (unsigned short*)(ws + 61464576);    // [M][512]
  unsigned short* scp = (unsigned short*)(ws + 122904576);   // [M][512]
  unsigned short* w1a = (unsigned short*)(ws + 184344576);   // [128][256]
  unsigned short* w3t = (unsigned short*)(ws + 184410112);   // [27][128][128] d-major
  unsigned short* w1b = (unsigned short*)(ws + 185294848);   // [512][128]
  unsigned short* wc  = (unsigned short*)(ws + 185425920);   // [512][256]
  float* ss1  = (float*)(ws + 185688064);
  float* ss2  = (float*)(ws + 185692160);
  float* ss3  = (float*)(ws + 185696256);
  float* sssc = (float*)(ws + 185700352);

  // Partials live in ws regions that are dead at their point of use:
  float* part12 = (float*)c3p;   // stage-1/2 stats (c3p not yet written)
  float* part3  = (float*)scp;   // stage-3 stats (read before gemmsc writes scp)
  float* partsc = (float*)wP;    // shortcut stats (wP dead after bnrelu2)

  prep_weights<<<1728, 256, 0, stream>>>(W1a, W3, W1b, Wc, w1a, w3t, w1b, wc);
  transpose_x<<<dim3(MT, 4), 256, 0, stream>>>(x, h, M);

  const int total = M * 128, total2 = (MT * 64) * 128;
  const int bnGrid = (total2 / 8 + 255) / 256;

  // c1 = relu(bn(h @ W1a^T))   (wA pad rows zeroed for octree gather)
  gemm128<<<MTO, 512, 0, stream>>>(h, w1a, wP, part12, M, 256, 128, 1);
  bn_finalize<<<128, 256, 0, stream>>>(part12, MTO, 128, M, g1a, b1a, ss1);
  bnrelu<<<bnGrid, 256, 0, stream>>>(wP, ss1, wA, total, total2, 127);

  // c2 = relu(bn(octree_conv(c1)))
  octree_gemm<<<MTO, 512, 0, stream>>>(wA, neigh, w3t, wP, part12, M);
  bn_finalize<<<128, 256, 0, stream>>>(part12, MTO, 128, M, g3, b3, ss2);
  bnrelu<<<bnGrid, 256, 0, stream>>>(wP, ss2, wA, total, total2, 127);

  // c3_pre = c2 @ W1b^T (stats -> part3, consumed before gemmsc writes scp)
  gemm128<<<4 * MTO, 512, 0, stream>>>(wA, w1b, c3p, part3, M, 128, 512, 4);
  bn_finalize<<<512, 256, 0, stream>>>(part3, MTO, 512, M, g1b, b1b, ss3);

  // sc_pre = h @ Wc^T
  gemm128<<<4 * MTO, 512, 0, stream>>>(h, wc, scp, partsc, M, 256, 512, 4);
  bn_finalize<<<512, 256, 0, stream>>>(partsc, MTO, 512, M, gc, bc, sssc);

  // out = relu(bn(c3_pre) + bn(sc_pre)), transposed to [512][M]
  final_out<<<dim3(MT, 4), 256, 0, stream>>>(c3p, scp, ss3, sssc, out, M);
}

// Round 10
// 225.644 us; speedup vs baseline: 5.4560x; 1.0510x over previous
//
#include <hip/hip_runtime.h>

// ---------------------------------------------------------------------------
// OctreeResBlock on MI355X (gfx950), round 9:
//  - r9 lesson: fp8 gather fails accuracy (0.234 > 0.155) — byte-halving dead.
//    Octree reverted to r8 bf16 (69us, random-gather fabric ceiling).
//  - NEW: octree is latency-bound with idle issue slots (469 blocks all
//    co-resident). Fuse the independent shortcut GEMM (h@Wc^T) into the same
//    launch: blocks [0,MTO) octree, rest sc-GEMM -> sc traffic hides under
//    the gather's latency window.
//  - prep_weights + transpose_x merged into one launch.
// ---------------------------------------------------------------------------

typedef __bf16 bf16x8 __attribute__((ext_vector_type(8)));
typedef float f32x4 __attribute__((ext_vector_type(4)));
typedef unsigned short u16x8 __attribute__((ext_vector_type(8)));
typedef unsigned short u16x4 __attribute__((ext_vector_type(4)));

__device__ __forceinline__ unsigned short f2bfu(float f) {
  union { float f; unsigned u; } v; v.f = f;
  unsigned r = v.u + 0x7fffu + ((v.u >> 16) & 1u);   // round-to-nearest-even
  return (unsigned short)(r >> 16);
}
__device__ __forceinline__ float bfu2f(unsigned short s) {
  union { unsigned u; float f; } v; v.u = ((unsigned)s) << 16;
  return v.f;
}

// async global->LDS, 16B per lane; dest = wave-uniform base + lane*16
__device__ __forceinline__ void gload_lds16(const unsigned short* g, unsigned short* l) {
  __builtin_amdgcn_global_load_lds(
      (const __attribute__((address_space(1))) unsigned int*)(unsigned long long)g,
      (__attribute__((address_space(3))) unsigned int*)(unsigned int)(unsigned long long)l,
      16, 0, 0);
}

// bijective chunked XCD swizzle (m204)
__device__ __forceinline__ int xcd_swz(int bid, int nwg) {
  int q = nwg >> 3, r = nwg & 7;
  int xcd = bid & 7, idx = bid >> 3;
  int base = xcd < r ? xcd * (q + 1) : r * (q + 1) + (xcd - r) * q;
  return base + idx;
}

// --- fused: weights fp32->bf16 (+W3 transpose) | x transpose to h -----------
__global__ __launch_bounds__(256) void prep_transpose(
    const float* __restrict__ x, unsigned short* __restrict__ h,
    const float* __restrict__ W1a, const float* __restrict__ W3,
    const float* __restrict__ W1b, const float* __restrict__ Wc,
    unsigned short* __restrict__ w1a, unsigned short* __restrict__ w3t,
    unsigned short* __restrict__ w1b, unsigned short* __restrict__ wc,
    int M, int MT) {
  __shared__ float tile[64][65];
  int t = threadIdx.x;
  if (blockIdx.x < 432) {
    int i = blockIdx.x * 256 + t;
    for (; i < 442368; i += 432 * 256) {
      if (i < 32768)  w1a[i] = f2bfu(W1a[i]);
      if (i < 65536)  w1b[i] = f2bfu(W1b[i]);
      if (i < 131072) wc[i]  = f2bfu(Wc[i]);
      int k = i >> 14, rr = i & 16383;
      int d = rr >> 7, c = rr & 127;
      w3t[i] = f2bfu(W3[(k << 14) + (c << 7) + d]);
    }
    return;
  }
  int bid = blockIdx.x - 432;
  int n0 = (bid % MT) * 64, c0 = (bid / MT) * 64;
  int nl = t & 63;
#pragma unroll
  for (int i = 0; i < 16; ++i) {
    int cl = i * 4 + (t >> 6);
    int n = n0 + nl;
    tile[cl][nl] = (n < M) ? x[(size_t)(c0 + cl) * M + n] : 0.f;
  }
  __syncthreads();
  int cl = t & 63;
#pragma unroll
  for (int i = 0; i < 16; ++i) {
    int nl2 = i * 4 + (t >> 6);
    int n = n0 + nl2;
    h[(size_t)n * 256 + c0 + cl] = f2bfu(tile[cl][nl2]);   // pad rows get zeros
  }
}

// --- dense GEMM: C[M][Nc] = A[Mpad][Kd] * W[Nc][Kd]^T (r8 structure) --------
__global__ __launch_bounds__(512, 4) void gemm128(
    const unsigned short* __restrict__ A, const unsigned short* __restrict__ W,
    unsigned short* __restrict__ C, float* __restrict__ partials,
    int M, int Kd, int Nc, int ncol) {
  __shared__ unsigned short sA[2][128 * 64];
  __shared__ unsigned short sB[2][128 * 64];
  __shared__ float sStat[8][2][128];
  int t = threadIdx.x, wave = t >> 6, lane = t & 63;
  int flat = xcd_swz(blockIdx.x, gridDim.x);
  int n0 = (flat % ncol) * 128;
  int rowt = flat / ncol;
  int m0 = rowt * 128;
  int wr = wave >> 1, wcc = wave & 1;
  int l4 = lane >> 4, lc = lane & 15, lc7 = lc & 7;
  int lrow = lane >> 3, lch = lane & 7;
  f32x4 acc[2][4] = {};
  const int np = Kd >> 6;

  auto STAGE = [&](int p, int buf) {
    int k0 = p << 6;
#pragma unroll
    for (int i = 0; i < 2; ++i) {
      int row = wave * 16 + i * 8 + lrow;
      int sc = lch ^ (row & 7);
      gload_lds16(A + (size_t)(m0 + row) * Kd + k0 + sc * 8, &sA[buf][(wave * 16 + i * 8) * 64]);
    }
#pragma unroll
    for (int i = 0; i < 2; ++i) {
      int row = wave * 16 + i * 8 + lrow;
      int sc = lch ^ (row & 7);
      gload_lds16(W + (size_t)(n0 + row) * Kd + k0 + sc * 8, &sB[buf][(wave * 16 + i * 8) * 64]);
    }
  };
  auto COMPUTE = [&](int buf) {
#pragma unroll
    for (int kk = 0; kk < 2; ++kk) {
      bf16x8 af[2], bfr[4];
#pragma unroll
      for (int mi = 0; mi < 2; ++mi) {
        int row = wr * 32 + mi * 16 + lc;
        int chunk = (kk * 4 + l4) ^ lc7;
        af[mi] = __builtin_bit_cast(bf16x8, *(const u16x8*)(&sA[buf][row * 64 + chunk * 8]));
      }
#pragma unroll
      for (int ni = 0; ni < 4; ++ni) {
        int row = wcc * 64 + ni * 16 + lc;
        int chunk = (kk * 4 + l4) ^ lc7;
        bfr[ni] = __builtin_bit_cast(bf16x8, *(const u16x8*)(&sB[buf][row * 64 + chunk * 8]));
      }
      __builtin_amdgcn_s_setprio(1);
#pragma unroll
      for (int mi = 0; mi < 2; ++mi)
#pragma unroll
        for (int ni = 0; ni < 4; ++ni)
          acc[mi][ni] = __builtin_amdgcn_mfma_f32_16x16x32_bf16(af[mi], bfr[ni], acc[mi][ni], 0, 0, 0);
      __builtin_amdgcn_s_setprio(0);
    }
  };

  STAGE(0, 0);
  for (int p = 0; p < np; ++p) {
    int cur = p & 1;
    if (p < np - 1) {
      STAGE(p + 1, cur ^ 1);
      asm volatile("s_waitcnt vmcnt(4)" ::: "memory");
    } else {
      asm volatile("s_waitcnt vmcnt(0)" ::: "memory");
    }
    __builtin_amdgcn_sched_barrier(0);
    __builtin_amdgcn_s_barrier();
    __builtin_amdgcn_sched_barrier(0);
    COMPUTE(cur);
    __builtin_amdgcn_sched_barrier(0);
    __builtin_amdgcn_s_barrier();
  }

#pragma unroll
  for (int ni = 0; ni < 4; ++ni) {
    float s = 0.f, q = 0.f;
    int col = wcc * 64 + ni * 16 + lc;
#pragma unroll
    for (int mi = 0; mi < 2; ++mi)
#pragma unroll
      for (int j = 0; j < 4; ++j) {
        int n = m0 + wr * 32 + mi * 16 + l4 * 4 + j;
        unsigned short u = f2bfu(acc[mi][ni][j]);
        if (n < M) C[(size_t)n * Nc + n0 + col] = u;
        float v = bfu2f(u);
        s += v; q += v * v;
      }
    s += __shfl_xor(s, 16); s += __shfl_xor(s, 32);
    q += __shfl_xor(q, 16); q += __shfl_xor(q, 32);
    if (lane < 16) {
      sStat[wave][0][col] = s;
      sStat[wave][1][col] = q;
    }
  }
  __syncthreads();
  if (t < 128) {
    int wcs = t >> 6;
    float s = 0.f, q = 0.f;
#pragma unroll
    for (int g = 0; g < 4; ++g) {
      s += sStat[g * 2 + wcs][0][t];
      q += sStat[g * 2 + wcs][1][t];
    }
    partials[(size_t)rowt * (2 * Nc) + n0 + t] = s;
    partials[(size_t)rowt * (2 * Nc) + Nc + n0 + t] = q;
  }
}

// --- FUSED: octree conv (blocks [0,MTO)) | shortcut GEMM (rest) -------------
// Octree: c2p[n][d] = sum_k sum_c c1[neigh[n][k]][c] * w3t[k][d][c] (r8 path).
// SC: scp = h @ wc^T (Kd=256, Nc=512, ncol=4). SC blocks stream through the
// issue slots octree's latency-bound blocks leave idle.
__global__ __launch_bounds__(512, 4) void octree_sc(
    const unsigned short* __restrict__ c1, const int* __restrict__ neigh,
    const unsigned short* __restrict__ w3t, unsigned short* __restrict__ c2p,
    float* __restrict__ part12,
    const unsigned short* __restrict__ h, const unsigned short* __restrict__ wc,
    unsigned short* __restrict__ scp, float* __restrict__ partsc,
    int M, int MTO) {
  __shared__ unsigned short sA[2][128 * 64];
  __shared__ unsigned short sB[2][128 * 64];
  __shared__ union {
    unsigned short nidx[128 * 27];
    float stat[8][2][128];
  } u;
  int t = threadIdx.x, wave = t >> 6, lane = t & 63;
  int wr = wave >> 1, wcc = wave & 1;
  int l4 = lane >> 4, lc = lane & 15, lc7 = lc & 7;
  int lrow = lane >> 3, lch = lane & 7;
  f32x4 acc[2][4] = {};

  if (blockIdx.x < (unsigned)MTO) {
    // ---------------- octree path ----------------
    int rowt = blockIdx.x;
    int m0 = rowt * 128;
    for (int i = t; i < 128 * 27; i += 512) {
      int row = i / 27;
      u.nidx[i] = (unsigned short)((m0 + row < M) ? neigh[(size_t)m0 * 27 + i] : M);
    }
    __syncthreads();

    auto STAGE = [&](int p, int buf) {
      int k = p >> 1, c0 = (p & 1) << 6;
#pragma unroll
      for (int i = 0; i < 2; ++i) {
        int row = wave * 16 + i * 8 + lrow;
        int nr = u.nidx[row * 27 + k];
        int sc = lch ^ (row & 7);
        gload_lds16(c1 + ((size_t)nr << 7) + c0 + sc * 8, &sA[buf][(wave * 16 + i * 8) * 64]);
      }
      const unsigned short* wk = w3t + ((size_t)k << 14);
#pragma unroll
      for (int i = 0; i < 2; ++i) {
        int row = wave * 16 + i * 8 + lrow;
        int sc = lch ^ (row & 7);
        gload_lds16(wk + ((size_t)row << 7) + c0 + sc * 8, &sB[buf][(wave * 16 + i * 8) * 64]);
      }
    };
    auto COMPUTE = [&](int buf) {
#pragma unroll
      for (int kk = 0; kk < 2; ++kk) {
        bf16x8 af[2], bfr[4];
#pragma unroll
        for (int mi = 0; mi < 2; ++mi) {
          int row = wr * 32 + mi * 16 + lc;
          int chunk = (kk * 4 + l4) ^ lc7;
          af[mi] = __builtin_bit_cast(bf16x8, *(const u16x8*)(&sA[buf][row * 64 + chunk * 8]));
        }
#pragma unroll
        for (int ni = 0; ni < 4; ++ni) {
          int row = wcc * 64 + ni * 16 + lc;
          int chunk = (kk * 4 + l4) ^ lc7;
          bfr[ni] = __builtin_bit_cast(bf16x8, *(const u16x8*)(&sB[buf][row * 64 + chunk * 8]));
        }
        __builtin_amdgcn_s_setprio(1);
#pragma unroll
        for (int mi = 0; mi < 2; ++mi)
#pragma unroll
          for (int ni = 0; ni < 4; ++ni)
            acc[mi][ni] = __builtin_amdgcn_mfma_f32_16x16x32_bf16(af[mi], bfr[ni], acc[mi][ni], 0, 0, 0);
        __builtin_amdgcn_s_setprio(0);
      }
    };

    STAGE(0, 0);
    for (int p = 0; p < 54; ++p) {
      int cur = p & 1;
      if (p < 53) {
        STAGE(p + 1, cur ^ 1);
        asm volatile("s_waitcnt vmcnt(4)" ::: "memory");
      } else {
        asm volatile("s_waitcnt vmcnt(0)" ::: "memory");
      }
      __builtin_amdgcn_sched_barrier(0);
      __builtin_amdgcn_s_barrier();
      __builtin_amdgcn_sched_barrier(0);
      COMPUTE(cur);
      __builtin_amdgcn_sched_barrier(0);
      __builtin_amdgcn_s_barrier();
    }

#pragma unroll
    for (int ni = 0; ni < 4; ++ni) {
      float s = 0.f, q = 0.f;
      int col = wcc * 64 + ni * 16 + lc;
#pragma unroll
      for (int mi = 0; mi < 2; ++mi)
#pragma unroll
        for (int j = 0; j < 4; ++j) {
          int n = m0 + wr * 32 + mi * 16 + l4 * 4 + j;
          unsigned short uo = f2bfu(acc[mi][ni][j]);
          if (n < M) c2p[(size_t)n * 128 + col] = uo;
          float v = bfu2f(uo);
          s += v; q += v * v;
        }
      s += __shfl_xor(s, 16); s += __shfl_xor(s, 32);
      q += __shfl_xor(q, 16); q += __shfl_xor(q, 32);
      if (lane < 16) {
        u.stat[wave][0][col] = s;
        u.stat[wave][1][col] = q;
      }
    }
    __syncthreads();
    if (t < 128) {
      int wcs = t >> 6;
      float s = 0.f, q = 0.f;
#pragma unroll
      for (int g = 0; g < 4; ++g) {
        s += u.stat[g * 2 + wcs][0][t];
        q += u.stat[g * 2 + wcs][1][t];
      }
      part12[(size_t)rowt * 256 + t] = s;
      part12[(size_t)rowt * 256 + 128 + t] = q;
    }
    return;
  }

  // ---------------- shortcut GEMM path (Kd=256, Nc=512, ncol=4) ----------------
  {
    int flat = xcd_swz(blockIdx.x - MTO, gridDim.x - MTO);
    int n0 = (flat & 3) * 128;
    int rowt = flat >> 2;
    int m0 = rowt * 128;

    auto STAGE = [&](int p, int buf) {
      int k0 = p << 6;
#pragma unroll
      for (int i = 0; i < 2; ++i) {
        int row = wave * 16 + i * 8 + lrow;
        int sc = lch ^ (row & 7);
        gload_lds16(h + (size_t)(m0 + row) * 256 + k0 + sc * 8, &sA[buf][(wave * 16 + i * 8) * 64]);
      }
#pragma unroll
      for (int i = 0; i < 2; ++i) {
        int row = wave * 16 + i * 8 + lrow;
        int sc = lch ^ (row & 7);
        gload_lds16(wc + (size_t)(n0 + row) * 256 + k0 + sc * 8, &sB[buf][(wave * 16 + i * 8) * 64]);
      }
    };
    auto COMPUTE = [&](int buf) {
#pragma unroll
      for (int kk = 0; kk < 2; ++kk) {
        bf16x8 af[2], bfr[4];
#pragma unroll
        for (int mi = 0; mi < 2; ++mi) {
          int row = wr * 32 + mi * 16 + lc;
          int chunk = (kk * 4 + l4) ^ lc7;
          af[mi] = __builtin_bit_cast(bf16x8, *(const u16x8*)(&sA[buf][row * 64 + chunk * 8]));
        }
#pragma unroll
        for (int ni = 0; ni < 4; ++ni) {
          int row = wcc * 64 + ni * 16 + lc;
          int chunk = (kk * 4 + l4) ^ lc7;
          bfr[ni] = __builtin_bit_cast(bf16x8, *(const u16x8*)(&sB[buf][row * 64 + chunk * 8]));
        }
        __builtin_amdgcn_s_setprio(1);
#pragma unroll
        for (int mi = 0; mi < 2; ++mi)
#pragma unroll
          for (int ni = 0; ni < 4; ++ni)
            acc[mi][ni] = __builtin_amdgcn_mfma_f32_16x16x32_bf16(af[mi], bfr[ni], acc[mi][ni], 0, 0, 0);
        __builtin_amdgcn_s_setprio(0);
      }
    };

    STAGE(0, 0);
    for (int p = 0; p < 4; ++p) {
      int cur = p & 1;
      if (p < 3) {
        STAGE(p + 1, cur ^ 1);
        asm volatile("s_waitcnt vmcnt(4)" ::: "memory");
      } else {
        asm volatile("s_waitcnt vmcnt(0)" ::: "memory");
      }
      __builtin_amdgcn_sched_barrier(0);
      __builtin_amdgcn_s_barrier();
      __builtin_amdgcn_sched_barrier(0);
      COMPUTE(cur);
      __builtin_amdgcn_sched_barrier(0);
      __builtin_amdgcn_s_barrier();
    }

#pragma unroll
    for (int ni = 0; ni < 4; ++ni) {
      float s = 0.f, q = 0.f;
      int col = wcc * 64 + ni * 16 + lc;
#pragma unroll
      for (int mi = 0; mi < 2; ++mi)
#pragma unroll
        for (int j = 0; j < 4; ++j) {
          int n = m0 + wr * 32 + mi * 16 + l4 * 4 + j;
          unsigned short uo = f2bfu(acc[mi][ni][j]);
          if (n < M) scp[(size_t)n * 512 + n0 + col] = uo;
          float v = bfu2f(uo);
          s += v; q += v * v;
        }
      s += __shfl_xor(s, 16); s += __shfl_xor(s, 32);
      q += __shfl_xor(q, 16); q += __shfl_xor(q, 32);
      if (lane < 16) {
        u.stat[wave][0][col] = s;
        u.stat[wave][1][col] = q;
      }
    }
    __syncthreads();
    if (t < 128) {
      int wcs = t >> 6;
      float s = 0.f, q = 0.f;
#pragma unroll
      for (int g = 0; g < 4; ++g) {
        s += u.stat[g * 2 + wcs][0][t];
        q += u.stat[g * 2 + wcs][1][t];
      }
      partsc[(size_t)rowt * 1024 + n0 + t] = s;
      partsc[(size_t)rowt * 1024 + 512 + n0 + t] = q;
    }
  }
}

// --- reduce partials -> scale/shift, one block per channel ------------------
__global__ __launch_bounds__(256) void bn_finalize(
    const float* __restrict__ partials, int nb, int C, int M,
    const float* __restrict__ g, const float* __restrict__ bt,
    float* __restrict__ ss) {
  int c = blockIdx.x;
  int t = threadIdx.x;
  float s = 0.f, s2 = 0.f;
  for (int b = t; b < nb; b += 256) {
    s += partials[(size_t)b * 2 * C + c];
    s2 += partials[(size_t)b * 2 * C + C + c];
  }
#pragma unroll
  for (int off = 32; off >= 1; off >>= 1) {
    s += __shfl_xor(s, off);
    s2 += __shfl_xor(s2, off);
  }
  __shared__ float sh[4][2];
  int wave = t >> 6, lane = t & 63;
  if (lane == 0) { sh[wave][0] = s; sh[wave][1] = s2; }
  __syncthreads();
  if (t == 0) {
    s = sh[0][0] + sh[1][0] + sh[2][0] + sh[3][0];
    s2 = sh[0][1] + sh[1][1] + sh[2][1] + sh[3][1];
    float mean = s / (float)M;
    float var = s2 / (float)M - mean * mean;
    float sc = g[c] * rsqrtf(var + 1e-5f);
    ss[c] = sc;
    ss[C + c] = bt[c] - mean * sc;
  }
}

// --- elementwise BN + ReLU, bf16 in/out; zero-pads rows [M, Mpad) -----------
__global__ __launch_bounds__(256) void bnrelu(
    const unsigned short* __restrict__ P, const float* __restrict__ ss,
    unsigned short* __restrict__ Aout, int total, int total2, int Cmask) {
  int i = (blockIdx.x * 256 + threadIdx.x) * 8;
  if (i >= total2) return;
  u16x8 o = {0, 0, 0, 0, 0, 0, 0, 0};
  if (i < total) {
    u16x8 v = *(const u16x8*)(P + i);
    int c0 = i & Cmask;
    int C = Cmask + 1;
#pragma unroll
    for (int j = 0; j < 8; ++j) {
      float f = bfu2f(v[j]) * ss[c0 + j] + ss[C + c0 + j];
      o[j] = f2bfu(fmaxf(f, 0.f));
    }
  }
  *(u16x8*)(Aout + i) = o;
}

// --- final: out[c][n] = relu(bn3(c3p) + bnsc(scp)), transposed fp32 write ---
__global__ __launch_bounds__(256) void final_out(
    const unsigned short* __restrict__ c3p, const unsigned short* __restrict__ scp,
    const float* __restrict__ ss3, const float* __restrict__ sssc,
    float* __restrict__ out, int M) {
  __shared__ float tile[64][129];
  int n0 = blockIdx.x * 64, c0 = blockIdx.y * 128;
  int t = threadIdx.x;
  int rowg = t >> 5, cg = (t & 31) * 4;
#pragma unroll
  for (int ps = 0; ps < 8; ++ps) {
    int nl = ps * 8 + rowg;
    int n = n0 + nl;
    float v0 = 0.f, v1 = 0.f, v2 = 0.f, v3 = 0.f;
    if (n < M) {
      u16x4 a = *(const u16x4*)(c3p + (size_t)n * 512 + c0 + cg);
      u16x4 b = *(const u16x4*)(scp + (size_t)n * 512 + c0 + cg);
      int c = c0 + cg;
      v0 = fmaxf(bfu2f(a[0]) * ss3[c + 0] + ss3[512 + c + 0] + bfu2f(b[0]) * sssc[c + 0] + sssc[512 + c + 0], 0.f);
      v1 = fmaxf(bfu2f(a[1]) * ss3[c + 1] + ss3[512 + c + 1] + bfu2f(b[1]) * sssc[c + 1] + sssc[512 + c + 1], 0.f);
      v2 = fmaxf(bfu2f(a[2]) * ss3[c + 2] + ss3[512 + c + 2] + bfu2f(b[2]) * sssc[c + 2] + sssc[512 + c + 2], 0.f);
      v3 = fmaxf(bfu2f(a[3]) * ss3[c + 3] + ss3[512 + c + 3] + bfu2f(b[3]) * sssc[c + 3] + sssc[512 + c + 3], 0.f);
    }
    tile[nl][cg + 0] = v0;
    tile[nl][cg + 1] = v1;
    tile[nl][cg + 2] = v2;
    tile[nl][cg + 3] = v3;
  }
  __syncthreads();
  int nl = t & 63, cq = t >> 6;
  int n = n0 + nl;
  if (n < M) {
#pragma unroll
    for (int i = 0; i < 32; ++i) {
      int cl = i * 4 + cq;
      out[(size_t)(c0 + cl) * M + n] = tile[nl][cl];
    }
  }
}

extern "C" void kernel_launch(void* const* d_in, const int* in_sizes, int n_in,
                              void* d_out, int out_size, void* d_ws, size_t ws_size,
                              hipStream_t stream) {
  const float* x   = (const float*)d_in[0];
  const int* neigh = (const int*)d_in[1];
  const float* W1a = (const float*)d_in[2];
  const float* g1a = (const float*)d_in[3];
  const float* b1a = (const float*)d_in[4];
  const float* W3  = (const float*)d_in[5];
  const float* g3  = (const float*)d_in[6];
  const float* b3  = (const float*)d_in[7];
  const float* W1b = (const float*)d_in[8];
  const float* g1b = (const float*)d_in[9];
  const float* b1b = (const float*)d_in[10];
  const float* Wc  = (const float*)d_in[11];
  const float* gc  = (const float*)d_in[12];
  const float* bc  = (const float*)d_in[13];
  float* out = (float*)d_out;

  const int M = in_sizes[1] / 27;          // 60000 nodes (< 65536: nidx ushort)
  const int MT = (M + 63) / 64;            // 938 (transpose/final tiles)
  const int MTO = (M + 127) / 128;         // 469 (GEMM row tiles)
  // Mpad = MT*64 = MTO*128 = 60032

  char* ws = (char*)d_ws;
  unsigned short* h   = (unsigned short*)(ws + 0);           // [60032][256] bf16
  unsigned short* wA  = (unsigned short*)(ws + 30736384);    // [60032][128]
  unsigned short* wP  = (unsigned short*)(ws + 46104576);    // [M][128]
  unsigned short* c3p = (unsigned short*)(ws + 61464576);    // [M][512]
  unsigned short* scp = (unsigned short*)(ws + 122904576);   // [M][512]
  unsigned short* w1a = (unsigned short*)(ws + 184344576);   // [128][256]
  unsigned short* w3t = (unsigned short*)(ws + 184410112);   // [27][128][128] d-major
  unsigned short* w1b = (unsigned short*)(ws + 185294848);   // [512][128]
  unsigned short* wc  = (unsigned short*)(ws + 185425920);   // [512][256]
  float* ss1  = (float*)(ws + 185688064);
  float* ss2  = (float*)(ws + 185692160);
  float* ss3  = (float*)(ws + 185696256);
  float* sssc = (float*)(ws + 185700352);

  // Partials in ws regions dead at their point of use:
  float* part1  = (float*)(ws + 61464576);             // c3p+0   (gemm1 stats)
  float* part12 = (float*)(ws + 61464576 + 1048576);   // c3p+1MB (octree stats)
  float* partsc = (float*)(ws + 61464576 + 2097152);   // c3p+2MB (sc stats)
  float* part3  = (float*)wP;                          // wP dead after bnrelu2

  prep_transpose<<<432 + MT * 4, 256, 0, stream>>>(
      x, h, W1a, W3, W1b, Wc, w1a, w3t, w1b, wc, M, MT);

  const int total = M * 128, total2 = (MT * 64) * 128;
  const int bnGrid = (total2 / 8 + 255) / 256;

  // c1 = relu(bn(h @ W1a^T))   (wA pad rows zeroed for octree gather)
  gemm128<<<MTO, 512, 0, stream>>>(h, w1a, wP, part1, M, 256, 128, 1);
  bn_finalize<<<128, 256, 0, stream>>>(part1, MTO, 128, M, g1a, b1a, ss1);
  bnrelu<<<bnGrid, 256, 0, stream>>>(wP, ss1, wA, total, total2, 127);

  // FUSED: c2_pre = octree_conv(c1)  ||  sc_pre = h @ Wc^T
  octree_sc<<<MTO + 4 * MTO, 512, 0, stream>>>(
      wA, neigh, w3t, wP, part12, h, wc, scp, partsc, M, MTO);
  bn_finalize<<<128, 256, 0, stream>>>(part12, MTO, 128, M, g3, b3, ss2);
  bn_finalize<<<512, 256, 0, stream>>>(partsc, MTO, 512, M, gc, bc, sssc);
  bnrelu<<<bnGrid, 256, 0, stream>>>(wP, ss2, wA, total, total2, 127);

  // c3_pre = c2 @ W1b^T (stats -> part3 in wP region, dead after bnrelu2)
  gemm128<<<4 * MTO, 512, 0, stream>>>(wA, w1b, c3p, part3, M, 128, 512, 4);
  bn_finalize<<<512, 256, 0, stream>>>(part3, MTO, 512, M, g1b, b1b, ss3);

  // out = relu(bn(c3_pre) + bn(sc_pre)), transposed to [512][M]
  final_out<<<dim3(MT, 4), 256, 0, stream>>>(c3p, scp, ss3, sssc, out, M);
}